// Round 10
// baseline (714.808 us; speedup 1.0000x reference)
//
#include <hip/hip_runtime.h>
#include <hip/hip_fp16.h>

// Problem constants
static constexpr int kN = 50000;      // nodes per side
static constexpr int kE = 800000;     // edges per side
static constexpr int kG = 1024;       // graphs per batch
static constexpr int kEMB = 128;
static constexpr int kGH = 256;
static constexpr int kEH = 256;
static constexpr int kOUT = 128;
static constexpr int kHID = 512;
static constexpr int kNB = (kN + 255) / 256;   // 196 scan chunks per side
static constexpr int kRankBlocks = kE / 256;   // 3125 (exact)

typedef __attribute__((ext_vector_type(8))) _Float16 half8v;
typedef __attribute__((ext_vector_type(4))) _Float16 half4v;
typedef __attribute__((ext_vector_type(4))) float floatx4;

// NOTE (R6): cross-XCD plain-data handoff through grid.sync() gave stale reads
// (per-XCD L2 non-coherence). Plain-store handoff only across kernel dispatches;
// ATOMIC-only protocols (scan2 below) are the one safe in-dispatch channel.
// NOTE (R7): device atomics execute memory-side; each dirties a 64B line
// (WRITE_SIZE ~= n_atomics*64), throughput ~21 ops/ns. Minimize atomic COUNT.
// NOTE (R8): rank trick — the counting atomic's return value is the edge's rank
// within its dst, so CSR fill needs no second atomic pass.

// ---------------------------------------------------------------------------
// Merged prep + rank. Blocks [0, 6250): rank pass (one returning atomic/edge).
// Blocks [6250, 6517): w2t = fp16(gW2^T) and M11 = atom_emb@gW1.
// ---------------------------------------------------------------------------
__global__ void prep_rank_kernel(const int* __restrict__ ei1, const int* __restrict__ ei2,
                                 int* __restrict__ counts, int* __restrict__ rankb,
                                 const float* __restrict__ atom_emb,
                                 const float* __restrict__ gW1, const float* __restrict__ gW2,
                                 float* __restrict__ M11, _Float16* __restrict__ w2t) {
    int b = blockIdx.x;
    if (b < 2 * kRankBlocks) {
        int side = b >= kRankBlocks;
        int i = (b - side * kRankBlocks) * 256 + threadIdx.x;   // < kE exactly
        const int* dst = (side ? ei2 : ei1) + kE;
        rankb[(size_t)side * kE + i] = atomicAdd(&counts[side * kN + dst[i]], 1);
    } else {
        int b2 = b - 2 * kRankBlocks;
        int i = b2 * 256 + threadIdx.x;
        if (b2 < 256) {
            int k = i >> 8, n = i & 255;
            w2t[(size_t)n * kGH + k] = (_Float16)gW2[(size_t)k * kGH + n];
        } else {
            int j = i - 65536;
            if (j < 11 * kGH) {
                int r = j >> 8, c = j & 255;
                float s = 0.f;
                for (int k = 0; k < kEMB; k++) s += atom_emb[r * kEMB + k] * gW1[k * kGH + c];
                M11[j] = s;
            }
        }
    }
}

// ---------------------------------------------------------------------------
// Single-dispatch scan via decoupled look-back (atomic-only cross-block
// protocol; all 392 blocks co-resident -> forward progress guaranteed).
// lb[ch] = (status<<32)|sum : status 1 = aggregate ready, 2 = prefix ready.
// Outputs row_ptr, dinv, xd (consumed by later dispatches -> plain stores OK).
// ---------------------------------------------------------------------------
__global__ void scan2_kernel(const int* __restrict__ counts, unsigned long long* __restrict__ lb,
                             int* __restrict__ row_ptr, float* __restrict__ dinv,
                             int2* __restrict__ xd,
                             const int* __restrict__ x1, const int* __restrict__ x2) {
    int ch = blockIdx.x;              // 0 .. 2*kNB-1 ; look-back never crosses sides
    int side = ch >= kNB;
    int lc = ch - side * kNB;
    const int* c = counts + side * kN;
    int* rp = row_ptr + side * (kN + 1);
    int t = threadIdx.x;
    int i = lc * 256 + t;
    __shared__ int s[256];
    __shared__ int pfx_s;
    int v = (i < kN) ? c[i] : 0;
    s[t] = v;
    __syncthreads();
    for (int o = 1; o < 256; o <<= 1) {
        int u = (t >= o) ? s[t - o] : 0;
        __syncthreads();
        s[t] += u;
        __syncthreads();
    }
    int total = s[255];
    if (t == 0) {
        if (lc == 0) {
            atomicExch(&lb[ch], (2ULL << 32) | (unsigned long long)(unsigned)total);
            pfx_s = 0;
        } else {
            atomicExch(&lb[ch], (1ULL << 32) | (unsigned long long)(unsigned)total);
            int prefix = 0;
            int pred = ch - 1;
            while (true) {
                unsigned long long pv = atomicAdd(&lb[pred], 0ULL);
                unsigned st = (unsigned)(pv >> 32);
                if (st == 0) continue;               // predecessor not published yet
                prefix += (int)(unsigned)(pv & 0xffffffffULL);
                if (st == 2u) break;                 // full prefix found
                pred--;
            }
            atomicExch(&lb[ch], (2ULL << 32) | (unsigned long long)(unsigned)(prefix + total));
            pfx_s = prefix;
        }
    }
    __syncthreads();
    int boff = pfx_s;
    if (i < kN) {
        rp[i + 1] = boff + s[t];
        float dv = rsqrtf((float)(v + 1));           // +1 self-loop
        dinv[side * kN + i] = dv;
        const int* x = side ? x2 : x1;
        xd[side * kN + i] = make_int2(x[i], __float_as_int(dv));
    }
    if (i == 0) rp[0] = 0;
}

// ---------------------------------------------------------------------------
// CSR scatter: plain stores, zero atomics (pos = row_ptr[d] + rank[e]).
// ---------------------------------------------------------------------------
__global__ void scatter_kernel(const int* __restrict__ ei1, const int* __restrict__ ei2,
                               const int* __restrict__ row_ptr, const int* __restrict__ rank,
                               int* __restrict__ col_idx) {
    int side = blockIdx.y;
    const int* ei = side ? ei2 : ei1;
    const int* rp = row_ptr + side * (kN + 1);
    int i = blockIdx.x * blockDim.x + threadIdx.x;
    if (i >= kE) return;
    int s = ei[i];           // src
    int d = ei[kE + i];      // dst
    int pos = rp[d] + rank[(size_t)side * kE + i];
    col_idx[(size_t)side * kE + pos] = s;
}

// ---------------------------------------------------------------------------
// Conv1 combine with in-kernel 11-bin histogram (zero atomics).
// h2[v] = relu(dv*(dv*M11[x[v]] + sum_t w[t]*M11[t]) + b1)
// ---------------------------------------------------------------------------
__global__ void conv1_combine_kernel(const int2* __restrict__ xd,
                                     const int* __restrict__ row_ptr,
                                     const int* __restrict__ col_idx,
                                     const float* __restrict__ M11,
                                     const float* __restrict__ bias,
                                     _Float16* __restrict__ out) {
    int side = blockIdx.y;
    const int2* xdb = xd + (size_t)side * kN;
    const int* rp = row_ptr + side * (kN + 1);
    const int* ci = col_idx + (size_t)side * kE;
    _Float16* ob = out + (size_t)side * kN * kGH;

    int wave = threadIdx.x >> 6;
    int lane = threadIdx.x & 63;
    int v = blockIdx.x * 4 + wave;
    if (v >= kN) return;

    int e0 = rp[v], e1 = rp[v + 1];
    float wt[11];
    #pragma unroll
    for (int t = 0; t < 11; t++) wt[t] = 0.f;
    for (int base = e0; base < e1; base += 64) {
        int e = base + lane;
        int xs = 15; float ds = 0.f;
        if (e < e1) {
            int2 t = xdb[ci[e]];
            xs = t.x; ds = __int_as_float(t.y);
        }
        #pragma unroll
        for (int t = 0; t < 11; t++) wt[t] += (xs == t) ? ds : 0.f;
    }
    #pragma unroll
    for (int t = 0; t < 11; t++) {
        float s = wt[t];
        #pragma unroll
        for (int o = 1; o < 64; o <<= 1) s += __shfl_xor(s, o);
        wt[t] = s;
    }

    int c = lane * 4;
    float4 bia = *(const float4*)(bias + c);
    int2 xv = xdb[v];
    float dv = __int_as_float(xv.y);
    float4 m = *(const float4*)(M11 + xv.x * kGH + c);
    float4 acc = make_float4(dv * m.x, dv * m.y, dv * m.z, dv * m.w);
    #pragma unroll
    for (int t = 0; t < 11; t++) {
        float w = wt[t];
        float4 mt = *(const float4*)(M11 + t * kGH + c);
        acc.x += w * mt.x; acc.y += w * mt.y;
        acc.z += w * mt.z; acc.w += w * mt.w;
    }
    half4v o;
    o[0] = (_Float16)fmaxf(dv * acc.x + bia.x, 0.f);
    o[1] = (_Float16)fmaxf(dv * acc.y + bia.y, 0.f);
    o[2] = (_Float16)fmaxf(dv * acc.z + bia.z, 0.f);
    o[3] = (_Float16)fmaxf(dv * acc.w + bia.w, 0.f);
    *(half4v*)(ob + (size_t)v * kGH + c) = o;
}

// ---------------------------------------------------------------------------
// Conv2 GEMM via MFMA f16, LDS-tiled: hs = dinv ⊙ (h2 @ W2)
// BM=128, BN=256 (full width -> A read ONCE), BK=64. 4 waves (2 row × 2 col
// halves); wave = 64 rows × 128 cols = 4×8 MFMA tiles.
// ---------------------------------------------------------------------------
__launch_bounds__(256)
__global__ void gemm2_mfma_kernel(const _Float16* __restrict__ A,
                                  const _Float16* __restrict__ Bt,
                                  const float* __restrict__ dinv,
                                  _Float16* __restrict__ C) {
    __shared__ _Float16 As[128][72];
    __shared__ _Float16 Bs[256][72];

    int side = blockIdx.y;
    const _Float16* Ab = A + (size_t)side * kN * kGH;
    const float* db = dinv + (size_t)side * kN;
    _Float16* Cb = C + (size_t)side * kN * kGH;

    int tid = threadIdx.x;
    int wave = tid >> 6, lane = tid & 63;
    int quad = lane >> 4, r = lane & 15;
    int wm = wave & 1;      // row half
    int wn = wave >> 1;     // col half
    int row0 = blockIdx.x * 128;

    floatx4 acc[4][8];
    #pragma unroll
    for (int i = 0; i < 4; i++)
        #pragma unroll
        for (int j = 0; j < 8; j++) acc[i][j] = (floatx4){0.f, 0.f, 0.f, 0.f};

    for (int k0 = 0; k0 < kGH; k0 += 64) {
        #pragma unroll
        for (int u = 0; u < 4; u++) {            // A tile 128x64
            int idx = tid + u * 256;
            int row = idx >> 3;
            int seg = (idx & 7) * 8;
            int gr = row0 + row;
            if (gr >= kN) gr = kN - 1;
            *(half8v*)&As[row][seg] = *(const half8v*)(Ab + (size_t)gr * kGH + k0 + seg);
        }
        #pragma unroll
        for (int u = 0; u < 8; u++) {            // B tile 256x64 (n-major)
            int idx = tid + u * 256;
            int row = idx >> 3;
            int seg = (idx & 7) * 8;
            *(half8v*)&Bs[row][seg] = *(const half8v*)(Bt + (size_t)row * kGH + k0 + seg);
        }
        __syncthreads();
        #pragma unroll
        for (int ks = 0; ks < 2; ks++) {
            half8v af[4], bf[8];
            #pragma unroll
            for (int mt = 0; mt < 4; mt++)
                af[mt] = *(const half8v*)&As[wm * 64 + mt * 16 + r][ks * 32 + quad * 8];
            #pragma unroll
            for (int nt = 0; nt < 8; nt++)
                bf[nt] = *(const half8v*)&Bs[wn * 128 + nt * 16 + r][ks * 32 + quad * 8];
            #pragma unroll
            for (int mt = 0; mt < 4; mt++)
                #pragma unroll
                for (int nt = 0; nt < 8; nt++)
                    acc[mt][nt] = __builtin_amdgcn_mfma_f32_16x16x32_f16(af[mt], bf[nt],
                                                                         acc[mt][nt], 0, 0, 0);
        }
        __syncthreads();
    }

    // Epilogue: C/D layout col = r, row = quad*4 + i
    #pragma unroll
    for (int mt = 0; mt < 4; mt++) {
        #pragma unroll
        for (int i = 0; i < 4; i++) {
            int grow = row0 + wm * 64 + mt * 16 + quad * 4 + i;
            if (grow >= kN) continue;
            float rs = db[grow];
            #pragma unroll
            for (int nt = 0; nt < 8; nt++) {
                int gcol = wn * 128 + nt * 16 + r;
                Cb[(size_t)grow * kGH + gcol] = (_Float16)(acc[mt][nt][i] * rs);
            }
        }
    }
}

// ---------------------------------------------------------------------------
// Conv2 aggregate: h4[v] = relu(dinv[v]*(hs[v] + sum_s hs[s]) + b2)  (hs fp16)
// Near the combined cache+HBM gather roofline; 16-wide ILP.
// ---------------------------------------------------------------------------
__global__ void aggregate2_kernel(const _Float16* __restrict__ hs, const float* __restrict__ dinv,
                                  const int* __restrict__ row_ptr, const int* __restrict__ col_idx,
                                  const float* __restrict__ bias, _Float16* __restrict__ out) {
    int side = blockIdx.y;
    const _Float16* hb = hs + (size_t)side * kN * kGH;
    const float* dv_ = dinv + side * kN;
    const int* rp = row_ptr + side * (kN + 1);
    const int* ci = col_idx + (size_t)side * kE;
    _Float16* ob = out + (size_t)side * kN * kGH;

    int wave = threadIdx.x >> 6;
    int lane = threadIdx.x & 63;
    int v = blockIdx.x * 4 + wave;
    if (v >= kN) return;
    int c = lane * 4;
    float4 bia = *(const float4*)(bias + c);
    float dv = dv_[v];
    half4v hv = *(const half4v*)(hb + (size_t)v * kGH + c);   // self-loop term
    float a0 = (float)hv[0], a1 = (float)hv[1], a2 = (float)hv[2], a3 = (float)hv[3];
    int e0 = rp[v], e1 = rp[v + 1];
    for (int base = e0; base < e1; base += 64) {
        int cnt = min(64, e1 - base);
        int idxl = (base + lane < e1) ? ci[base + lane] : 0;
        int j = 0;
        for (; j + 16 <= cnt; j += 16) {
            half4v h[16];
            #pragma unroll
            for (int u = 0; u < 16; u++)
                h[u] = *(const half4v*)(hb + (size_t)__shfl(idxl, j + u) * kGH + c);
            #pragma unroll
            for (int u = 0; u < 16; u++) {
                a0 += (float)h[u][0]; a1 += (float)h[u][1];
                a2 += (float)h[u][2]; a3 += (float)h[u][3];
            }
        }
        for (; j + 8 <= cnt; j += 8) {
            half4v h[8];
            #pragma unroll
            for (int u = 0; u < 8; u++)
                h[u] = *(const half4v*)(hb + (size_t)__shfl(idxl, j + u) * kGH + c);
            #pragma unroll
            for (int u = 0; u < 8; u++) {
                a0 += (float)h[u][0]; a1 += (float)h[u][1];
                a2 += (float)h[u][2]; a3 += (float)h[u][3];
            }
        }
        for (; j < cnt; j++) {
            half4v h = *(const half4v*)(hb + (size_t)__shfl(idxl, j) * kGH + c);
            a0 += (float)h[0]; a1 += (float)h[1]; a2 += (float)h[2]; a3 += (float)h[3];
        }
    }
    half4v o;
    o[0] = (_Float16)fmaxf(dv * a0 + bia.x, 0.f);
    o[1] = (_Float16)fmaxf(dv * a1 + bia.y, 0.f);
    o[2] = (_Float16)fmaxf(dv * a2 + bia.z, 0.f);
    o[3] = (_Float16)fmaxf(dv * a3 + bia.w, 0.f);
    *(half4v*)(ob + (size_t)v * kGH + c) = o;
}

// ---------------------------------------------------------------------------
// Merged dispatch: y<2 -> fused mean-pool + fc; y==2 -> eW1 GEMM with fused
// entity gather+relu on the A-load (independent roles, one launch).
// ---------------------------------------------------------------------------
__launch_bounds__(256)
__global__ void poolfc_ent_kernel(const _Float16* __restrict__ h,
                                  const int* __restrict__ batch1, const int* __restrict__ batch2,
                                  const float* __restrict__ fcW, const float* __restrict__ fcb,
                                  float* __restrict__ gfc,
                                  const float* __restrict__ emb,
                                  const int* __restrict__ ent1, const int* __restrict__ ent2,
                                  const float* __restrict__ eW1, float* __restrict__ etmp,
                                  const float* __restrict__ eb1) {
    __shared__ float As[16][64];
    __shared__ float Bs[16][64];
    __shared__ float ps[256];

    if (blockIdx.y == 2) {
        if (blockIdx.x >= 128) return;        // 32 row-blocks x 4 col-blocks
        int tid = threadIdx.x;
        int tx = tid & 15, ty = tid >> 4;
        int row0 = (blockIdx.x >> 2) * 64, col0 = (blockIdx.x & 3) * 64;
        float acc[4][4] = {};
        for (int k0 = 0; k0 < kEMB; k0 += 16) {
            {
                int r = tid >> 2, seg = tid & 3;
                int gr = row0 + r;             // < 2G always
                int idx = (gr < kG) ? ent1[gr] : ent2[gr - kG];
                float4 v = *(const float4*)(emb + (size_t)idx * kEMB + k0 + seg * 4);
                As[seg * 4 + 0][r] = fmaxf(v.x, 0.f); As[seg * 4 + 1][r] = fmaxf(v.y, 0.f);
                As[seg * 4 + 2][r] = fmaxf(v.z, 0.f); As[seg * 4 + 3][r] = fmaxf(v.w, 0.f);
            }
            {
                int kr = tid >> 4, c4 = (tid & 15) * 4;
                float4 v = *(const float4*)(eW1 + (size_t)(k0 + kr) * kEH + col0 + c4);
                *(float4*)&Bs[kr][c4] = v;
            }
            __syncthreads();
            #pragma unroll
            for (int k = 0; k < 16; k++) {
                float a[4], b[4];
                #pragma unroll
                for (int i = 0; i < 4; i++) a[i] = As[k][ty * 4 + i];
                #pragma unroll
                for (int j = 0; j < 4; j++) b[j] = Bs[k][tx * 4 + j];
                #pragma unroll
                for (int i = 0; i < 4; i++)
                    #pragma unroll
                    for (int j = 0; j < 4; j++)
                        acc[i][j] += a[i] * b[j];
            }
            __syncthreads();
        }
        #pragma unroll
        for (int i = 0; i < 4; i++) {
            int gr = row0 + ty * 4 + i;
            #pragma unroll
            for (int j = 0; j < 4; j++) {
                int gc = col0 + tx * 4 + j;
                etmp[(size_t)gr * kEH + gc] = fmaxf(acc[i][j] + eb1[gc], 0.f);
            }
        }
        return;
    }

    // poolfc role
    int side = blockIdx.y;
    const _Float16* hb = h + (size_t)side * kN * kGH;
    const int* batch = side ? batch2 : batch1;
    int g = blockIdx.x;
    int lo = 0, hi = kN;
    while (lo < hi) { int mid = (lo + hi) >> 1; if (batch[mid] < g) lo = mid + 1; else hi = mid; }
    int start = lo;
    lo = start; hi = kN;
    while (lo < hi) { int mid = (lo + hi) >> 1; if (batch[mid] < g + 1) lo = mid + 1; else hi = mid; }
    int end = lo;
    int c = threadIdx.x;  // 256
    float s = 0.f;
    for (int v = start; v < end; v++) s += (float)hb[(size_t)v * kGH + c];
    ps[c] = s / fmaxf((float)(end - start), 1.0f);
    __syncthreads();
    float acc = fcb[c];
    #pragma unroll 4
    for (int k = 0; k < kGH; k++) acc += ps[k] * fcW[(size_t)k * kGH + c];
    gfc[(size_t)(side * kG + g) * kGH + c] = acc;
}

// ---------------------------------------------------------------------------
// Generic tiled fp32 GEMM (tail layers): C = (A@B) [+bias] [relu]
// ---------------------------------------------------------------------------
__launch_bounds__(256)
__global__ void gemm_kernel(const float* __restrict__ A, const float* __restrict__ B,
                            float* __restrict__ C, int M, int N, int K,
                            const float* __restrict__ bias, int relu) {
    __shared__ float As[16][64];
    __shared__ float Bs[16][64];
    int tid = threadIdx.x;
    int tx = tid & 15, ty = tid >> 4;
    int row0 = blockIdx.y * 64, col0 = blockIdx.x * 64;
    float acc[4][4] = {};
    for (int k0 = 0; k0 < K; k0 += 16) {
        {
            int r = tid >> 2, seg = tid & 3;
            int gr = row0 + r;
            float4 v = make_float4(0.f, 0.f, 0.f, 0.f);
            if (gr < M) v = *(const float4*)(A + (size_t)gr * K + k0 + seg * 4);
            As[seg * 4 + 0][r] = v.x; As[seg * 4 + 1][r] = v.y;
            As[seg * 4 + 2][r] = v.z; As[seg * 4 + 3][r] = v.w;
        }
        {
            int kr = tid >> 4, c4 = (tid & 15) * 4;
            float4 v = *(const float4*)(B + (size_t)(k0 + kr) * N + col0 + c4);
            *(float4*)&Bs[kr][c4] = v;
        }
        __syncthreads();
        #pragma unroll
        for (int k = 0; k < 16; k++) {
            float a[4], b[4];
            #pragma unroll
            for (int i = 0; i < 4; i++) a[i] = As[k][ty * 4 + i];
            #pragma unroll
            for (int j = 0; j < 4; j++) b[j] = Bs[k][tx * 4 + j];
            #pragma unroll
            for (int i = 0; i < 4; i++)
                #pragma unroll
                for (int j = 0; j < 4; j++)
                    acc[i][j] += a[i] * b[j];
        }
        __syncthreads();
    }
    #pragma unroll
    for (int i = 0; i < 4; i++) {
        int gr = row0 + ty * 4 + i;
        if (gr >= M) continue;
        #pragma unroll
        for (int j = 0; j < 4; j++) {
            int gc = col0 + tx * 4 + j;
            float v = acc[i][j];
            if (bias) v += bias[gc];
            if (relu) v = fmaxf(v, 0.f);
            C[(size_t)gr * N + gc] = v;
        }
    }
}

// ---------------------------------------------------------------------------
// dW1 GEMM with fused egs computation on the A-load.
// ---------------------------------------------------------------------------
__launch_bounds__(256)
__global__ void gemm_egs_kernel(const float* __restrict__ gfc, const float* __restrict__ ento,
                                const float* __restrict__ B, float* __restrict__ C,
                                int N, const float* __restrict__ bias) {
    __shared__ float As[16][64];
    __shared__ float Bs[16][64];
    int tid = threadIdx.x;
    int tx = tid & 15, ty = tid >> 4;
    int row0 = blockIdx.y * 64, col0 = blockIdx.x * 64;
    float acc[4][4] = {};
    for (int k0 = 0; k0 < kHID; k0 += 16) {
        {
            int r = tid >> 2, seg = tid & 3;
            int gr = row0 + r;                 // < G always
            int k = k0 + seg * 4;
            float4 va, vb;
            if (k < kGH) {
                va = *(const float4*)(gfc + (size_t)gr * kGH + k);
                vb = *(const float4*)(gfc + (size_t)(gr + kG) * kGH + k);
            } else {
                va = *(const float4*)(ento + (size_t)gr * kEH + k - kGH);
                vb = *(const float4*)(ento + (size_t)(gr + kG) * kEH + k - kGH);
            }
            As[seg * 4 + 0][r] = fmaxf(va.x + vb.x, 0.f);
            As[seg * 4 + 1][r] = fmaxf(va.y + vb.y, 0.f);
            As[seg * 4 + 2][r] = fmaxf(va.z + vb.z, 0.f);
            As[seg * 4 + 3][r] = fmaxf(va.w + vb.w, 0.f);
        }
        {
            int kr = tid >> 4, c4 = (tid & 15) * 4;
            float4 v = *(const float4*)(B + (size_t)(k0 + kr) * N + col0 + c4);
            *(float4*)&Bs[kr][c4] = v;
        }
        __syncthreads();
        #pragma unroll
        for (int k = 0; k < 16; k++) {
            float a[4], b[4];
            #pragma unroll
            for (int i = 0; i < 4; i++) a[i] = As[k][ty * 4 + i];
            #pragma unroll
            for (int j = 0; j < 4; j++) b[j] = Bs[k][tx * 4 + j];
            #pragma unroll
            for (int i = 0; i < 4; i++)
                #pragma unroll
                for (int j = 0; j < 4; j++)
                    acc[i][j] += a[i] * b[j];
        }
        __syncthreads();
    }
    #pragma unroll
    for (int i = 0; i < 4; i++) {
        int gr = row0 + ty * 4 + i;
        #pragma unroll
        for (int j = 0; j < 4; j++) {
            int gc = col0 + tx * 4 + j;
            C[(size_t)gr * N + gc] = fmaxf(acc[i][j] + bias[gc], 0.f);
        }
    }
}

// ---------------------------------------------------------------------------
// Host launch
// ---------------------------------------------------------------------------
static inline char* carve(char*& p, size_t bytes) {
    char* r = p;
    p += (bytes + 255) & ~(size_t)255;
    return r;
}

extern "C" void kernel_launch(void* const* d_in, const int* in_sizes, int n_in,
                              void* d_out, int out_size, void* d_ws, size_t ws_size,
                              hipStream_t stream) {
    const int*   x1       = (const int*)d_in[0];
    const int*   ei1      = (const int*)d_in[1];
    const int*   ent1     = (const int*)d_in[2];
    const int*   batch1   = (const int*)d_in[3];
    const int*   x2       = (const int*)d_in[4];
    const int*   ei2      = (const int*)d_in[5];
    const int*   ent2     = (const int*)d_in[6];
    const int*   batch2   = (const int*)d_in[7];
    const float* atom_emb = (const float*)d_in[8];
    const float* gW1      = (const float*)d_in[9];
    const float* gb1      = (const float*)d_in[10];
    const float* gW2      = (const float*)d_in[11];
    const float* gb2      = (const float*)d_in[12];
    const float* fcW      = (const float*)d_in[13];
    const float* fcb      = (const float*)d_in[14];
    const float* ent_emb  = (const float*)d_in[15];
    const float* eW1      = (const float*)d_in[16];
    const float* eb1      = (const float*)d_in[17];
    const float* eW2      = (const float*)d_in[18];
    const float* eb2      = (const float*)d_in[19];
    const float* dW1      = (const float*)d_in[20];
    const float* db1      = (const float*)d_in[21];
    const float* dW2      = (const float*)d_in[22];
    const float* db2      = (const float*)d_in[23];
    const float* dW3      = (const float*)d_in[24];
    const float* db3      = (const float*)d_in[25];
    float* out = (float*)d_out;

    // Workspace carve; counts + lb form the single zeroed span.
    char* p = (char*)d_ws;
    _Float16* h2_h   = (_Float16*)carve(p, (size_t)2 * kN * kGH * 2);  // also h4
    _Float16* hs_h   = (_Float16*)carve(p, (size_t)2 * kN * kGH * 2);
    int*   col_idx = (int*)  carve(p, (size_t)2 * kE * 4);
    int*   rankb   = (int*)  carve(p, (size_t)2 * kE * 4);
    int*   row_ptr = (int*)  carve(p, (size_t)2 * (kN + 1) * 4);
    int*   counts  = (int*)  carve(p, (size_t)2 * kN * 4);
    unsigned long long* lb = (unsigned long long*)carve(p, (size_t)2 * kNB * 8);
    char*  zend    = p;                       // end of zeroed span
    float* dinv    = (float*)carve(p, (size_t)2 * kN * 4);
    int2*  xd      = (int2*) carve(p, (size_t)2 * kN * 8);
    float* M11     = (float*)carve(p, 11 * kGH * 4);
    _Float16* w2t  = (_Float16*)carve(p, (size_t)kGH * kGH * 2);
    float* gfc     = (float*)carve(p, (size_t)2 * kG * kGH * 4);
    float* etmp    = (float*)carve(p, (size_t)2 * kG * kEH * 4);
    float* ento    = (float*)carve(p, (size_t)2 * kG * kEH * 4);
    float* dh1     = (float*)carve(p, (size_t)kG * kHID * 4);
    float* dh2     = (float*)carve(p, (size_t)kG * kHID * 4);

    // --- Graph structure + conv1 ---
    hipMemsetAsync(counts, 0, (size_t)(zend - (char*)counts), stream);
    prep_rank_kernel<<<2 * kRankBlocks + 267, 256, 0, stream>>>(ei1, ei2, counts, rankb,
                                                                atom_emb, gW1, gW2, M11, w2t);
    scan2_kernel<<<2 * kNB, 256, 0, stream>>>(counts, lb, row_ptr, dinv, xd, x1, x2);
    scatter_kernel<<<dim3(kE / 256, 2), 256, 0, stream>>>(ei1, ei2, row_ptr, rankb, col_idx);
    conv1_combine_kernel<<<dim3((kN + 3) / 4, 2), 256, 0, stream>>>(xd, row_ptr, col_idx,
                                                                    M11, gb1, h2_h);

    // --- Conv2 GEMM (MFMA f16, BN=256): hs = dinv ⊙ (h2 @ W2) ---
    gemm2_mfma_kernel<<<dim3((kN + 127) / 128, 2), 256, 0, stream>>>(h2_h, w2t, dinv, hs_h);
    // --- Conv2 aggregate -> h4 (reuses h2 buffer) ---
    aggregate2_kernel<<<dim3((kN + 3) / 4, 2), 256, 0, stream>>>(hs_h, dinv, row_ptr, col_idx,
                                                                 gb2, h2_h);
    // --- Fused mean-pool+fc (y<2) and eW1 GEMM with entity gather (y==2) ---
    poolfc_ent_kernel<<<dim3(kG, 3), 256, 0, stream>>>(h2_h, batch1, batch2, fcW, fcb, gfc,
                                                       ent_emb, ent1, ent2, eW1, etmp, eb1);
    // --- Entity encoder layer 2 ---
    gemm_kernel<<<dim3(kEH / 64, 2 * kG / 64), 256, 0, stream>>>(etmp, eW2, ento,
                                                                 2 * kG, kEH, kEH, eb2, 1);
    // --- Decoder (egs fused into dW1) ---
    gemm_egs_kernel<<<dim3(kHID / 64, kG / 64), 256, 0, stream>>>(gfc, ento, dW1, dh1,
                                                                  kHID, db1);
    gemm_kernel<<<dim3(kHID / 64, kG / 64), 256, 0, stream>>>(dh1, dW2, dh2,
                                                              kG, kHID, kHID, db2, 1);
    gemm_kernel<<<dim3(kOUT / 64, kG / 64), 256, 0, stream>>>(dh2, dW3, out,
                                                              kG, kOUT, kHID, db3, 0);
}

// Round 11
// 687.169 us; speedup vs baseline: 1.0402x; 1.0402x over previous
//
#include <hip/hip_runtime.h>
#include <hip/hip_fp16.h>

// Problem constants
static constexpr int kN = 50000;      // nodes per side
static constexpr int kE = 800000;     // edges per side
static constexpr int kG = 1024;       // graphs per batch
static constexpr int kEMB = 128;
static constexpr int kGH = 256;
static constexpr int kEH = 256;
static constexpr int kOUT = 128;
static constexpr int kHID = 512;
static constexpr int kNB = (kN + 255) / 256;   // 196 scan chunks per side
static constexpr int kRankBlocks = kE / 256;   // 3125 (exact)

typedef __attribute__((ext_vector_type(8))) _Float16 half8v;
typedef __attribute__((ext_vector_type(4))) _Float16 half4v;
typedef __attribute__((ext_vector_type(4))) float floatx4;

// NOTE (R6): cross-XCD plain-data handoff through grid.sync() gave stale reads
// (per-XCD L2 non-coherence). Plain-store handoff only across kernel dispatches.
// NOTE (R7): device atomics execute memory-side; each dirties a 64B line
// (WRITE_SIZE ~= n_atomics*64), throughput ~21 ops/ns. Minimize atomic COUNT.
// NOTE (R8): rank trick — the counting atomic's return value is the edge's rank.
// NOTE (R10): decoupled-lookback scan REGRESSED (+40us: serial atomic polling
// chains at ~200-900 cyc/poll). BN=256 gemm2 REGRESSED (acc VGPR x2 -> occupancy
// collapse). Keep the 3-dispatch scan and BN=128.

// ---------------------------------------------------------------------------
// Merged prep + rank. Blocks [0, 6250): rank pass (one returning atomic/edge).
// Blocks [6250, 6517): w2t = fp16(gW2^T) and M11 = atom_emb@gW1.
// ---------------------------------------------------------------------------
__global__ void prep_rank_kernel(const int* __restrict__ ei1, const int* __restrict__ ei2,
                                 int* __restrict__ counts, int* __restrict__ rankb,
                                 const float* __restrict__ atom_emb,
                                 const float* __restrict__ gW1, const float* __restrict__ gW2,
                                 float* __restrict__ M11, _Float16* __restrict__ w2t) {
    int b = blockIdx.x;
    if (b < 2 * kRankBlocks) {
        int side = b >= kRankBlocks;
        int i = (b - side * kRankBlocks) * 256 + threadIdx.x;   // < kE exactly
        const int* dst = (side ? ei2 : ei1) + kE;
        rankb[(size_t)side * kE + i] = atomicAdd(&counts[side * kN + dst[i]], 1);
    } else {
        int b2 = b - 2 * kRankBlocks;
        int i = b2 * 256 + threadIdx.x;
        if (b2 < 256) {
            int k = i >> 8, n = i & 255;
            w2t[(size_t)n * kGH + k] = (_Float16)gW2[(size_t)k * kGH + n];
        } else {
            int j = i - 65536;
            if (j < 11 * kGH) {
                int r = j >> 8, c = j & 255;
                float s = 0.f;
                for (int k = 0; k < kEMB; k++) s += atom_emb[r * kEMB + k] * gW1[k * kGH + c];
                M11[j] = s;
            }
        }
    }
}

// Per-chunk sums (196 chunks per side)
__global__ void bsum_kernel(const int* __restrict__ counts, int* __restrict__ bsum) {
    int side = blockIdx.y;
    const int* c = counts + side * kN;
    int i = blockIdx.x * 256 + threadIdx.x;
    int v = (i < kN) ? c[i] : 0;
    #pragma unroll
    for (int o = 32; o; o >>= 1) v += __shfl_down(v, o);
    __shared__ int ws[4];
    if ((threadIdx.x & 63) == 0) ws[threadIdx.x >> 6] = v;
    __syncthreads();
    if (threadIdx.x == 0) bsum[side * kNB + blockIdx.x] = ws[0] + ws[1] + ws[2] + ws[3];
}

// Exclusive scan of the chunk sums (one block per side)
__global__ void bscan_kernel(const int* __restrict__ bsum, int* __restrict__ boff) {
    int side = blockIdx.x;
    __shared__ int s[256];
    int t = threadIdx.x;
    int v = (t < kNB) ? bsum[side * kNB + t] : 0;
    s[t] = v;
    __syncthreads();
    for (int o = 1; o < 256; o <<= 1) {
        int u = (t >= o) ? s[t - o] : 0;
        __syncthreads();
        s[t] += u;
        __syncthreads();
    }
    if (t < kNB) boff[side * kNB + t] = s[t] - v;   // exclusive
}

// Final: local inclusive scan per chunk + chunk offset -> row_ptr.
// Fused: dinv = rsqrt(deg+1) and xd[v] = (x[v], bits(dinv[v])).
__global__ void scanf_kernel(const int* __restrict__ counts, const int* __restrict__ boff,
                             int* __restrict__ row_ptr, float* __restrict__ dinv,
                             int2* __restrict__ xd,
                             const int* __restrict__ x1, const int* __restrict__ x2) {
    int side = blockIdx.y;
    const int* c = counts + side * kN;
    int* rp = row_ptr + side * (kN + 1);
    int t = threadIdx.x;
    int i = blockIdx.x * 256 + t;
    __shared__ int s[256];
    int v = (i < kN) ? c[i] : 0;
    s[t] = v;
    __syncthreads();
    for (int o = 1; o < 256; o <<= 1) {
        int u = (t >= o) ? s[t - o] : 0;
        __syncthreads();
        s[t] += u;
        __syncthreads();
    }
    if (i < kN) {
        rp[i + 1] = boff[side * kNB + blockIdx.x] + s[t];
        float dv = rsqrtf((float)(v + 1));           // +1 self-loop
        dinv[side * kN + i] = dv;
        const int* x = side ? x2 : x1;
        xd[side * kN + i] = make_int2(x[i], __float_as_int(dv));
    }
    if (i == 0) rp[0] = 0;
}

// ---------------------------------------------------------------------------
// CSR scatter: plain stores, zero atomics (pos = row_ptr[d] + rank[e]).
// ---------------------------------------------------------------------------
__global__ void scatter_kernel(const int* __restrict__ ei1, const int* __restrict__ ei2,
                               const int* __restrict__ row_ptr, const int* __restrict__ rank,
                               int* __restrict__ col_idx) {
    int side = blockIdx.y;
    const int* ei = side ? ei2 : ei1;
    const int* rp = row_ptr + side * (kN + 1);
    int i = blockIdx.x * blockDim.x + threadIdx.x;
    if (i >= kE) return;
    int s = ei[i];           // src
    int d = ei[kE + i];      // dst
    int pos = rp[d] + rank[(size_t)side * kE + i];
    col_idx[(size_t)side * kE + pos] = s;
}

// ---------------------------------------------------------------------------
// Conv1 combine with in-kernel 11-bin histogram (zero atomics).
// h2[v] = relu(dv*(dv*M11[x[v]] + sum_t w[t]*M11[t]) + b1)
// ---------------------------------------------------------------------------
__global__ void conv1_combine_kernel(const int2* __restrict__ xd,
                                     const int* __restrict__ row_ptr,
                                     const int* __restrict__ col_idx,
                                     const float* __restrict__ M11,
                                     const float* __restrict__ bias,
                                     _Float16* __restrict__ out) {
    int side = blockIdx.y;
    const int2* xdb = xd + (size_t)side * kN;
    const int* rp = row_ptr + side * (kN + 1);
    const int* ci = col_idx + (size_t)side * kE;
    _Float16* ob = out + (size_t)side * kN * kGH;

    int wave = threadIdx.x >> 6;
    int lane = threadIdx.x & 63;
    int v = blockIdx.x * 4 + wave;
    if (v >= kN) return;

    int e0 = rp[v], e1 = rp[v + 1];
    float wt[11];
    #pragma unroll
    for (int t = 0; t < 11; t++) wt[t] = 0.f;
    for (int base = e0; base < e1; base += 64) {
        int e = base + lane;
        int xs = 15; float ds = 0.f;
        if (e < e1) {
            int2 t = xdb[ci[e]];
            xs = t.x; ds = __int_as_float(t.y);
        }
        #pragma unroll
        for (int t = 0; t < 11; t++) wt[t] += (xs == t) ? ds : 0.f;
    }
    #pragma unroll
    for (int t = 0; t < 11; t++) {
        float s = wt[t];
        #pragma unroll
        for (int o = 1; o < 64; o <<= 1) s += __shfl_xor(s, o);
        wt[t] = s;
    }

    int c = lane * 4;
    float4 bia = *(const float4*)(bias + c);
    int2 xv = xdb[v];
    float dv = __int_as_float(xv.y);
    float4 m = *(const float4*)(M11 + xv.x * kGH + c);
    float4 acc = make_float4(dv * m.x, dv * m.y, dv * m.z, dv * m.w);
    #pragma unroll
    for (int t = 0; t < 11; t++) {
        float w = wt[t];
        float4 mt = *(const float4*)(M11 + t * kGH + c);
        acc.x += w * mt.x; acc.y += w * mt.y;
        acc.z += w * mt.z; acc.w += w * mt.w;
    }
    half4v o;
    o[0] = (_Float16)fmaxf(dv * acc.x + bia.x, 0.f);
    o[1] = (_Float16)fmaxf(dv * acc.y + bia.y, 0.f);
    o[2] = (_Float16)fmaxf(dv * acc.z + bia.z, 0.f);
    o[3] = (_Float16)fmaxf(dv * acc.w + bia.w, 0.f);
    *(half4v*)(ob + (size_t)v * kGH + c) = o;
}

// ---------------------------------------------------------------------------
// Conv2 GEMM via MFMA f16, LDS-tiled: hs = dinv ⊙ (h2 @ W2)
// BM=128, BN=128, BK=64 (R9-measured config). 4 waves (2x2); wave = 64x64.
// ---------------------------------------------------------------------------
__launch_bounds__(256)
__global__ void gemm2_mfma_kernel(const _Float16* __restrict__ A,
                                  const _Float16* __restrict__ Bt,
                                  const float* __restrict__ dinv,
                                  _Float16* __restrict__ C) {
    __shared__ _Float16 As[128][72];
    __shared__ _Float16 Bs[128][72];

    int side = blockIdx.z;
    const _Float16* Ab = A + (size_t)side * kN * kGH;
    const float* db = dinv + (size_t)side * kN;
    _Float16* Cb = C + (size_t)side * kN * kGH;

    int tid = threadIdx.x;
    int wave = tid >> 6, lane = tid & 63;
    int quad = lane >> 4, r = lane & 15;
    int wm = wave >> 1, wn = wave & 1;
    int row0 = blockIdx.x * 128;
    int col0 = blockIdx.y * 128;

    floatx4 acc[4][4];
    #pragma unroll
    for (int i = 0; i < 4; i++)
        #pragma unroll
        for (int j = 0; j < 4; j++) acc[i][j] = (floatx4){0.f, 0.f, 0.f, 0.f};

    for (int k0 = 0; k0 < kGH; k0 += 64) {
        #pragma unroll
        for (int u = 0; u < 4; u++) {
            int idx = tid + u * 256;           // 0..1023
            int row = idx >> 3;                // 0..127
            int seg = (idx & 7) * 8;           // 0..56
            int gr = row0 + row;
            if (gr >= kN) gr = kN - 1;
            *(half8v*)&As[row][seg] = *(const half8v*)(Ab + (size_t)gr * kGH + k0 + seg);
            *(half8v*)&Bs[row][seg] = *(const half8v*)(Bt + (size_t)(col0 + row) * kGH + k0 + seg);
        }
        __syncthreads();
        #pragma unroll
        for (int ks = 0; ks < 2; ks++) {
            half8v af[4], bf[4];
            #pragma unroll
            for (int mt = 0; mt < 4; mt++)
                af[mt] = *(const half8v*)&As[wm * 64 + mt * 16 + r][ks * 32 + quad * 8];
            #pragma unroll
            for (int nt = 0; nt < 4; nt++)
                bf[nt] = *(const half8v*)&Bs[wn * 64 + nt * 16 + r][ks * 32 + quad * 8];
            #pragma unroll
            for (int mt = 0; mt < 4; mt++)
                #pragma unroll
                for (int nt = 0; nt < 4; nt++)
                    acc[mt][nt] = __builtin_amdgcn_mfma_f32_16x16x32_f16(af[mt], bf[nt],
                                                                         acc[mt][nt], 0, 0, 0);
        }
        __syncthreads();
    }

    // Epilogue: C/D layout col = r, row = quad*4 + i
    #pragma unroll
    for (int mt = 0; mt < 4; mt++) {
        #pragma unroll
        for (int i = 0; i < 4; i++) {
            int grow = row0 + wm * 64 + mt * 16 + quad * 4 + i;
            if (grow >= kN) continue;
            float rs = db[grow];
            #pragma unroll
            for (int nt = 0; nt < 4; nt++) {
                int gcol = col0 + wn * 64 + nt * 16 + r;
                Cb[(size_t)grow * kGH + gcol] = (_Float16)(acc[mt][nt][i] * rs);
            }
        }
    }
}

// ---------------------------------------------------------------------------
// Conv2 aggregate: h4[v] = relu(dinv[v]*(hs[v] + sum_s hs[s]) + b2)  (hs fp16)
// Near the combined cache+HBM gather roofline; 16-wide ILP.
// ---------------------------------------------------------------------------
__global__ void aggregate2_kernel(const _Float16* __restrict__ hs, const float* __restrict__ dinv,
                                  const int* __restrict__ row_ptr, const int* __restrict__ col_idx,
                                  const float* __restrict__ bias, _Float16* __restrict__ out) {
    int side = blockIdx.y;
    const _Float16* hb = hs + (size_t)side * kN * kGH;
    const float* dv_ = dinv + side * kN;
    const int* rp = row_ptr + side * (kN + 1);
    const int* ci = col_idx + (size_t)side * kE;
    _Float16* ob = out + (size_t)side * kN * kGH;

    int wave = threadIdx.x >> 6;
    int lane = threadIdx.x & 63;
    int v = blockIdx.x * 4 + wave;
    if (v >= kN) return;
    int c = lane * 4;
    float4 bia = *(const float4*)(bias + c);
    float dv = dv_[v];
    half4v hv = *(const half4v*)(hb + (size_t)v * kGH + c);   // self-loop term
    float a0 = (float)hv[0], a1 = (float)hv[1], a2 = (float)hv[2], a3 = (float)hv[3];
    int e0 = rp[v], e1 = rp[v + 1];
    for (int base = e0; base < e1; base += 64) {
        int cnt = min(64, e1 - base);
        int idxl = (base + lane < e1) ? ci[base + lane] : 0;
        int j = 0;
        for (; j + 16 <= cnt; j += 16) {
            half4v h[16];
            #pragma unroll
            for (int u = 0; u < 16; u++)
                h[u] = *(const half4v*)(hb + (size_t)__shfl(idxl, j + u) * kGH + c);
            #pragma unroll
            for (int u = 0; u < 16; u++) {
                a0 += (float)h[u][0]; a1 += (float)h[u][1];
                a2 += (float)h[u][2]; a3 += (float)h[u][3];
            }
        }
        for (; j + 8 <= cnt; j += 8) {
            half4v h[8];
            #pragma unroll
            for (int u = 0; u < 8; u++)
                h[u] = *(const half4v*)(hb + (size_t)__shfl(idxl, j + u) * kGH + c);
            #pragma unroll
            for (int u = 0; u < 8; u++) {
                a0 += (float)h[u][0]; a1 += (float)h[u][1];
                a2 += (float)h[u][2]; a3 += (float)h[u][3];
            }
        }
        for (; j < cnt; j++) {
            half4v h = *(const half4v*)(hb + (size_t)__shfl(idxl, j) * kGH + c);
            a0 += (float)h[0]; a1 += (float)h[1]; a2 += (float)h[2]; a3 += (float)h[3];
        }
    }
    half4v o;
    o[0] = (_Float16)fmaxf(dv * a0 + bia.x, 0.f);
    o[1] = (_Float16)fmaxf(dv * a1 + bia.y, 0.f);
    o[2] = (_Float16)fmaxf(dv * a2 + bia.z, 0.f);
    o[3] = (_Float16)fmaxf(dv * a3 + bia.w, 0.f);
    *(half4v*)(ob + (size_t)v * kGH + c) = o;
}

// ---------------------------------------------------------------------------
// Merged dispatch: y<2 -> fused mean-pool + fc; y==2 -> eW1 GEMM with fused
// entity gather+relu on the A-load (independent roles, one launch).
// ---------------------------------------------------------------------------
__launch_bounds__(256)
__global__ void poolfc_ent_kernel(const _Float16* __restrict__ h,
                                  const int* __restrict__ batch1, const int* __restrict__ batch2,
                                  const float* __restrict__ fcW, const float* __restrict__ fcb,
                                  float* __restrict__ gfc,
                                  const float* __restrict__ emb,
                                  const int* __restrict__ ent1, const int* __restrict__ ent2,
                                  const float* __restrict__ eW1, float* __restrict__ etmp,
                                  const float* __restrict__ eb1) {
    __shared__ float As[16][64];
    __shared__ float Bs[16][64];
    __shared__ float ps[256];

    if (blockIdx.y == 2) {
        if (blockIdx.x >= 128) return;        // 32 row-blocks x 4 col-blocks
        int tid = threadIdx.x;
        int tx = tid & 15, ty = tid >> 4;
        int row0 = (blockIdx.x >> 2) * 64, col0 = (blockIdx.x & 3) * 64;
        float acc[4][4] = {};
        for (int k0 = 0; k0 < kEMB; k0 += 16) {
            {
                int r = tid >> 2, seg = tid & 3;
                int gr = row0 + r;             // < 2G always
                int idx = (gr < kG) ? ent1[gr] : ent2[gr - kG];
                float4 v = *(const float4*)(emb + (size_t)idx * kEMB + k0 + seg * 4);
                As[seg * 4 + 0][r] = fmaxf(v.x, 0.f); As[seg * 4 + 1][r] = fmaxf(v.y, 0.f);
                As[seg * 4 + 2][r] = fmaxf(v.z, 0.f); As[seg * 4 + 3][r] = fmaxf(v.w, 0.f);
            }
            {
                int kr = tid >> 4, c4 = (tid & 15) * 4;
                float4 v = *(const float4*)(eW1 + (size_t)(k0 + kr) * kEH + col0 + c4);
                *(float4*)&Bs[kr][c4] = v;
            }
            __syncthreads();
            #pragma unroll
            for (int k = 0; k < 16; k++) {
                float a[4], b[4];
                #pragma unroll
                for (int i = 0; i < 4; i++) a[i] = As[k][ty * 4 + i];
                #pragma unroll
                for (int j = 0; j < 4; j++) b[j] = Bs[k][tx * 4 + j];
                #pragma unroll
                for (int i = 0; i < 4; i++)
                    #pragma unroll
                    for (int j = 0; j < 4; j++)
                        acc[i][j] += a[i] * b[j];
            }
            __syncthreads();
        }
        #pragma unroll
        for (int i = 0; i < 4; i++) {
            int gr = row0 + ty * 4 + i;
            #pragma unroll
            for (int j = 0; j < 4; j++) {
                int gc = col0 + tx * 4 + j;
                etmp[(size_t)gr * kEH + gc] = fmaxf(acc[i][j] + eb1[gc], 0.f);
            }
        }
        return;
    }

    // poolfc role
    int side = blockIdx.y;
    const _Float16* hb = h + (size_t)side * kN * kGH;
    const int* batch = side ? batch2 : batch1;
    int g = blockIdx.x;
    int lo = 0, hi = kN;
    while (lo < hi) { int mid = (lo + hi) >> 1; if (batch[mid] < g) lo = mid + 1; else hi = mid; }
    int start = lo;
    lo = start; hi = kN;
    while (lo < hi) { int mid = (lo + hi) >> 1; if (batch[mid] < g + 1) lo = mid + 1; else hi = mid; }
    int end = lo;
    int c = threadIdx.x;  // 256
    float s = 0.f;
    for (int v = start; v < end; v++) s += (float)hb[(size_t)v * kGH + c];
    ps[c] = s / fmaxf((float)(end - start), 1.0f);
    __syncthreads();
    float acc = fcb[c];
    #pragma unroll 4
    for (int k = 0; k < kGH; k++) acc += ps[k] * fcW[(size_t)k * kGH + c];
    gfc[(size_t)(side * kG + g) * kGH + c] = acc;
}

// ---------------------------------------------------------------------------
// Generic tiled fp32 GEMM (tail layers): C = (A@B) [+bias] [relu]
// ---------------------------------------------------------------------------
__launch_bounds__(256)
__global__ void gemm_kernel(const float* __restrict__ A, const float* __restrict__ B,
                            float* __restrict__ C, int M, int N, int K,
                            const float* __restrict__ bias, int relu) {
    __shared__ float As[16][64];
    __shared__ float Bs[16][64];
    int tid = threadIdx.x;
    int tx = tid & 15, ty = tid >> 4;
    int row0 = blockIdx.y * 64, col0 = blockIdx.x * 64;
    float acc[4][4] = {};
    for (int k0 = 0; k0 < K; k0 += 16) {
        {
            int r = tid >> 2, seg = tid & 3;
            int gr = row0 + r;
            float4 v = make_float4(0.f, 0.f, 0.f, 0.f);
            if (gr < M) v = *(const float4*)(A + (size_t)gr * K + k0 + seg * 4);
            As[seg * 4 + 0][r] = v.x; As[seg * 4 + 1][r] = v.y;
            As[seg * 4 + 2][r] = v.z; As[seg * 4 + 3][r] = v.w;
        }
        {
            int kr = tid >> 4, c4 = (tid & 15) * 4;
            float4 v = *(const float4*)(B + (size_t)(k0 + kr) * N + col0 + c4);
            *(float4*)&Bs[kr][c4] = v;
        }
        __syncthreads();
        #pragma unroll
        for (int k = 0; k < 16; k++) {
            float a[4], b[4];
            #pragma unroll
            for (int i = 0; i < 4; i++) a[i] = As[k][ty * 4 + i];
            #pragma unroll
            for (int j = 0; j < 4; j++) b[j] = Bs[k][tx * 4 + j];
            #pragma unroll
            for (int i = 0; i < 4; i++)
                #pragma unroll
                for (int j = 0; j < 4; j++)
                    acc[i][j] += a[i] * b[j];
        }
        __syncthreads();
    }
    #pragma unroll
    for (int i = 0; i < 4; i++) {
        int gr = row0 + ty * 4 + i;
        if (gr >= M) continue;
        #pragma unroll
        for (int j = 0; j < 4; j++) {
            int gc = col0 + tx * 4 + j;
            float v = acc[i][j];
            if (bias) v += bias[gc];
            if (relu) v = fmaxf(v, 0.f);
            C[(size_t)gr * N + gc] = v;
        }
    }
}

// ---------------------------------------------------------------------------
// dW1 GEMM with fused egs computation on the A-load.
// ---------------------------------------------------------------------------
__launch_bounds__(256)
__global__ void gemm_egs_kernel(const float* __restrict__ gfc, const float* __restrict__ ento,
                                const float* __restrict__ B, float* __restrict__ C,
                                int N, const float* __restrict__ bias) {
    __shared__ float As[16][64];
    __shared__ float Bs[16][64];
    int tid = threadIdx.x;
    int tx = tid & 15, ty = tid >> 4;
    int row0 = blockIdx.y * 64, col0 = blockIdx.x * 64;
    float acc[4][4] = {};
    for (int k0 = 0; k0 < kHID; k0 += 16) {
        {
            int r = tid >> 2, seg = tid & 3;
            int gr = row0 + r;                 // < G always
            int k = k0 + seg * 4;
            float4 va, vb;
            if (k < kGH) {
                va = *(const float4*)(gfc + (size_t)gr * kGH + k);
                vb = *(const float4*)(gfc + (size_t)(gr + kG) * kGH + k);
            } else {
                va = *(const float4*)(ento + (size_t)gr * kEH + k - kGH);
                vb = *(const float4*)(ento + (size_t)(gr + kG) * kEH + k - kGH);
            }
            As[seg * 4 + 0][r] = fmaxf(va.x + vb.x, 0.f);
            As[seg * 4 + 1][r] = fmaxf(va.y + vb.y, 0.f);
            As[seg * 4 + 2][r] = fmaxf(va.z + vb.z, 0.f);
            As[seg * 4 + 3][r] = fmaxf(va.w + vb.w, 0.f);
        }
        {
            int kr = tid >> 4, c4 = (tid & 15) * 4;
            float4 v = *(const float4*)(B + (size_t)(k0 + kr) * N + col0 + c4);
            *(float4*)&Bs[kr][c4] = v;
        }
        __syncthreads();
        #pragma unroll
        for (int k = 0; k < 16; k++) {
            float a[4], b[4];
            #pragma unroll
            for (int i = 0; i < 4; i++) a[i] = As[k][ty * 4 + i];
            #pragma unroll
            for (int j = 0; j < 4; j++) b[j] = Bs[k][tx * 4 + j];
            #pragma unroll
            for (int i = 0; i < 4; i++)
                #pragma unroll
                for (int j = 0; j < 4; j++)
                    acc[i][j] += a[i] * b[j];
        }
        __syncthreads();
    }
    #pragma unroll
    for (int i = 0; i < 4; i++) {
        int gr = row0 + ty * 4 + i;
        #pragma unroll
        for (int j = 0; j < 4; j++) {
            int gc = col0 + tx * 4 + j;
            C[(size_t)gr * N + gc] = fmaxf(acc[i][j] + bias[gc], 0.f);
        }
    }
}

// ---------------------------------------------------------------------------
// Host launch
// ---------------------------------------------------------------------------
static inline char* carve(char*& p, size_t bytes) {
    char* r = p;
    p += (bytes + 255) & ~(size_t)255;
    return r;
}

extern "C" void kernel_launch(void* const* d_in, const int* in_sizes, int n_in,
                              void* d_out, int out_size, void* d_ws, size_t ws_size,
                              hipStream_t stream) {
    const int*   x1       = (const int*)d_in[0];
    const int*   ei1      = (const int*)d_in[1];
    const int*   ent1     = (const int*)d_in[2];
    const int*   batch1   = (const int*)d_in[3];
    const int*   x2       = (const int*)d_in[4];
    const int*   ei2      = (const int*)d_in[5];
    const int*   ent2     = (const int*)d_in[6];
    const int*   batch2   = (const int*)d_in[7];
    const float* atom_emb = (const float*)d_in[8];
    const float* gW1      = (const float*)d_in[9];
    const float* gb1      = (const float*)d_in[10];
    const float* gW2      = (const float*)d_in[11];
    const float* gb2      = (const float*)d_in[12];
    const float* fcW      = (const float*)d_in[13];
    const float* fcb      = (const float*)d_in[14];
    const float* ent_emb  = (const float*)d_in[15];
    const float* eW1      = (const float*)d_in[16];
    const float* eb1      = (const float*)d_in[17];
    const float* eW2      = (const float*)d_in[18];
    const float* eb2      = (const float*)d_in[19];
    const float* dW1      = (const float*)d_in[20];
    const float* db1      = (const float*)d_in[21];
    const float* dW2      = (const float*)d_in[22];
    const float* db2      = (const float*)d_in[23];
    const float* dW3      = (const float*)d_in[24];
    const float* db3      = (const float*)d_in[25];
    float* out = (float*)d_out;

    // Workspace carve; counts is the only zeroed span.
    char* p = (char*)d_ws;
    _Float16* h2_h   = (_Float16*)carve(p, (size_t)2 * kN * kGH * 2);  // also h4
    _Float16* hs_h   = (_Float16*)carve(p, (size_t)2 * kN * kGH * 2);
    int*   col_idx = (int*)  carve(p, (size_t)2 * kE * 4);
    int*   rankb   = (int*)  carve(p, (size_t)2 * kE * 4);
    int*   row_ptr = (int*)  carve(p, (size_t)2 * (kN + 1) * 4);
    int*   counts  = (int*)  carve(p, (size_t)2 * kN * 4);
    float* dinv    = (float*)carve(p, (size_t)2 * kN * 4);
    int2*  xd      = (int2*) carve(p, (size_t)2 * kN * 8);
    int*   bsum    = (int*)  carve(p, (size_t)2 * kNB * 4);
    int*   boff    = (int*)  carve(p, (size_t)2 * kNB * 4);
    float* M11     = (float*)carve(p, 11 * kGH * 4);
    _Float16* w2t  = (_Float16*)carve(p, (size_t)kGH * kGH * 2);
    float* gfc     = (float*)carve(p, (size_t)2 * kG * kGH * 4);
    float* etmp    = (float*)carve(p, (size_t)2 * kG * kEH * 4);
    float* ento    = (float*)carve(p, (size_t)2 * kG * kEH * 4);
    float* dh1     = (float*)carve(p, (size_t)kG * kHID * 4);
    float* dh2     = (float*)carve(p, (size_t)kG * kHID * 4);

    // --- Graph structure + conv1 (kernel boundaries = safe grid barriers) ---
    hipMemsetAsync(counts, 0, (size_t)2 * kN * 4, stream);
    prep_rank_kernel<<<2 * kRankBlocks + 267, 256, 0, stream>>>(ei1, ei2, counts, rankb,
                                                                atom_emb, gW1, gW2, M11, w2t);
    bsum_kernel<<<dim3(kNB, 2), 256, 0, stream>>>(counts, bsum);
    bscan_kernel<<<2, 256, 0, stream>>>(bsum, boff);
    scanf_kernel<<<dim3(kNB, 2), 256, 0, stream>>>(counts, boff, row_ptr, dinv, xd, x1, x2);
    scatter_kernel<<<dim3(kE / 256, 2), 256, 0, stream>>>(ei1, ei2, row_ptr, rankb, col_idx);
    conv1_combine_kernel<<<dim3((kN + 3) / 4, 2), 256, 0, stream>>>(xd, row_ptr, col_idx,
                                                                    M11, gb1, h2_h);

    // --- Conv2 GEMM (MFMA f16, BN=128): hs = dinv ⊙ (h2 @ W2) ---
    gemm2_mfma_kernel<<<dim3((kN + 127) / 128, kGH / 128, 2), 256, 0, stream>>>(h2_h, w2t,
                                                                                dinv, hs_h);
    // --- Conv2 aggregate -> h4 (reuses h2 buffer) ---
    aggregate2_kernel<<<dim3((kN + 3) / 4, 2), 256, 0, stream>>>(hs_h, dinv, row_ptr, col_idx,
                                                                 gb2, h2_h);
    // --- Fused mean-pool+fc (y<2) and eW1 GEMM with entity gather (y==2) ---
    poolfc_ent_kernel<<<dim3(kG, 3), 256, 0, stream>>>(h2_h, batch1, batch2, fcW, fcb, gfc,
                                                       ent_emb, ent1, ent2, eW1, etmp, eb1);
    // --- Entity encoder layer 2 ---
    gemm_kernel<<<dim3(kEH / 64, 2 * kG / 64), 256, 0, stream>>>(etmp, eW2, ento,
                                                                 2 * kG, kEH, kEH, eb2, 1);
    // --- Decoder (egs fused into dW1) ---
    gemm_egs_kernel<<<dim3(kHID / 64, kG / 64), 256, 0, stream>>>(gfc, ento, dW1, dh1,
                                                                  kHID, db1);
    gemm_kernel<<<dim3(kHID / 64, kG / 64), 256, 0, stream>>>(dh1, dW2, dh2,
                                                              kG, kHID, kHID, db2, 1);
    gemm_kernel<<<dim3(kOUT / 64, kG / 64), 256, 0, stream>>>(dh2, dW3, out,
                                                              kG, kOUT, kHID, db3, 0);
}

// Round 12
// 679.010 us; speedup vs baseline: 1.0527x; 1.0120x over previous
//
#include <hip/hip_runtime.h>
#include <hip/hip_fp16.h>

// Problem constants
static constexpr int kN = 50000;      // nodes per side
static constexpr int kE = 800000;     // edges per side
static constexpr int kG = 1024;       // graphs per batch
static constexpr int kEMB = 128;
static constexpr int kGH = 256;
static constexpr int kEH = 256;
static constexpr int kOUT = 128;
static constexpr int kHID = 512;
static constexpr int kNB = (kN + 255) / 256;   // 196 scan chunks per side
static constexpr int kCS = 16;                 // counts stride (ints) = 1 line/counter

typedef __attribute__((ext_vector_type(8))) _Float16 half8v;
typedef __attribute__((ext_vector_type(4))) _Float16 half4v;
typedef __attribute__((ext_vector_type(4))) float floatx4;

// NOTE (R6): cross-XCD plain-data handoff through grid.sync() gave stale reads.
// Phase boundaries are separate dispatches.
// NOTE (R7): device atomics execute memory-side; ~21 ops/ns measured; each
// dirties a 64B line. Minimize atomic COUNT.
// NOTE (R8): rank trick — counting atomic's return value = edge's rank in dst.
// NOTE (R10): decoupled-lookback scan regressed (serial atomic polling); BN=256
// gemm2 regressed (VGPR/occupancy). NOTE (R11): role-merged grids with
// heterogeneous block runtimes regressed ~13us. Keep R9 dispatch structure.
// R12 experiment: counts padded to one counter per 64B line (atomic
// line-serialization theory).

// ---------------------------------------------------------------------------
// prep: w2t = fp16(gW2^T) (blocks 0..255), M11 = atom_emb@gW1 (blocks 256..266)
// ---------------------------------------------------------------------------
__global__ void prep_kernel(const float* __restrict__ atom_emb, const float* __restrict__ gW1,
                            const float* __restrict__ gW2,
                            float* __restrict__ M11, _Float16* __restrict__ w2t) {
    int i = blockIdx.x * 256 + threadIdx.x;
    if (blockIdx.x < 256) {
        int k = i >> 8, n = i & 255;
        w2t[(size_t)n * kGH + k] = (_Float16)gW2[(size_t)k * kGH + n];
    } else {
        int j = i - 65536;
        if (j < 11 * kGH) {
            int r = j >> 8, c = j & 255;
            float s = 0.f;
            for (int k = 0; k < kEMB; k++) s += atom_emb[r * kEMB + k] * gW1[k * kGH + c];
            M11[j] = s;
        }
    }
}

// ---------------------------------------------------------------------------
// Rank pass: one returning atomic per edge; counters padded to 1/line.
// ---------------------------------------------------------------------------
__global__ void rank_kernel(const int* __restrict__ ei1, const int* __restrict__ ei2,
                            int* __restrict__ counts, int* __restrict__ rankb) {
    int side = blockIdx.y;
    const int* dst = (side ? ei2 : ei1) + kE;
    int i = blockIdx.x * blockDim.x + threadIdx.x;
    if (i >= kE) return;
    rankb[(size_t)side * kE + i] =
        atomicAdd(&counts[((size_t)side * kN + dst[i]) * kCS], 1);
}

// Per-chunk sums (196 chunks per side); counts strided by kCS
__global__ void bsum_kernel(const int* __restrict__ counts, int* __restrict__ bsum) {
    int side = blockIdx.y;
    const int* c = counts + (size_t)side * kN * kCS;
    int i = blockIdx.x * 256 + threadIdx.x;
    int v = (i < kN) ? c[(size_t)i * kCS] : 0;
    #pragma unroll
    for (int o = 32; o; o >>= 1) v += __shfl_down(v, o);
    __shared__ int ws[4];
    if ((threadIdx.x & 63) == 0) ws[threadIdx.x >> 6] = v;
    __syncthreads();
    if (threadIdx.x == 0) bsum[side * kNB + blockIdx.x] = ws[0] + ws[1] + ws[2] + ws[3];
}

// Exclusive scan of the chunk sums (one block per side)
__global__ void bscan_kernel(const int* __restrict__ bsum, int* __restrict__ boff) {
    int side = blockIdx.x;
    __shared__ int s[256];
    int t = threadIdx.x;
    int v = (t < kNB) ? bsum[side * kNB + t] : 0;
    s[t] = v;
    __syncthreads();
    for (int o = 1; o < 256; o <<= 1) {
        int u = (t >= o) ? s[t - o] : 0;
        __syncthreads();
        s[t] += u;
        __syncthreads();
    }
    if (t < kNB) boff[side * kNB + t] = s[t] - v;   // exclusive
}

// Final: local inclusive scan per chunk + chunk offset -> row_ptr.
// Fused: dinv = rsqrt(deg+1) and xd[v] = (x[v], bits(dinv[v])).
__global__ void scanf_kernel(const int* __restrict__ counts, const int* __restrict__ boff,
                             int* __restrict__ row_ptr, float* __restrict__ dinv,
                             int2* __restrict__ xd,
                             const int* __restrict__ x1, const int* __restrict__ x2) {
    int side = blockIdx.y;
    const int* c = counts + (size_t)side * kN * kCS;
    int* rp = row_ptr + side * (kN + 1);
    int t = threadIdx.x;
    int i = blockIdx.x * 256 + t;
    __shared__ int s[256];
    int v = (i < kN) ? c[(size_t)i * kCS] : 0;
    s[t] = v;
    __syncthreads();
    for (int o = 1; o < 256; o <<= 1) {
        int u = (t >= o) ? s[t - o] : 0;
        __syncthreads();
        s[t] += u;
        __syncthreads();
    }
    if (i < kN) {
        rp[i + 1] = boff[side * kNB + blockIdx.x] + s[t];
        float dv = rsqrtf((float)(v + 1));           // +1 self-loop
        dinv[side * kN + i] = dv;
        const int* x = side ? x2 : x1;
        xd[side * kN + i] = make_int2(x[i], __float_as_int(dv));
    }
    if (i == 0) rp[0] = 0;
}

// ---------------------------------------------------------------------------
// CSR scatter: plain stores, zero atomics (pos = row_ptr[d] + rank[e]).
// ---------------------------------------------------------------------------
__global__ void scatter_kernel(const int* __restrict__ ei1, const int* __restrict__ ei2,
                               const int* __restrict__ row_ptr, const int* __restrict__ rank,
                               int* __restrict__ col_idx) {
    int side = blockIdx.y;
    const int* ei = side ? ei2 : ei1;
    const int* rp = row_ptr + side * (kN + 1);
    int i = blockIdx.x * blockDim.x + threadIdx.x;
    if (i >= kE) return;
    int s = ei[i];           // src
    int d = ei[kE + i];      // dst
    int pos = rp[d] + rank[(size_t)side * kE + i];
    col_idx[(size_t)side * kE + pos] = s;
}

// ---------------------------------------------------------------------------
// Conv1 combine with in-kernel 11-bin histogram (zero atomics).
// h2[v] = relu(dv*(dv*M11[x[v]] + sum_t w[t]*M11[t]) + b1)
// ---------------------------------------------------------------------------
__global__ void conv1_combine_kernel(const int2* __restrict__ xd,
                                     const int* __restrict__ row_ptr,
                                     const int* __restrict__ col_idx,
                                     const float* __restrict__ M11,
                                     const float* __restrict__ bias,
                                     _Float16* __restrict__ out) {
    int side = blockIdx.y;
    const int2* xdb = xd + (size_t)side * kN;
    const int* rp = row_ptr + side * (kN + 1);
    const int* ci = col_idx + (size_t)side * kE;
    _Float16* ob = out + (size_t)side * kN * kGH;

    int wave = threadIdx.x >> 6;
    int lane = threadIdx.x & 63;
    int v = blockIdx.x * 4 + wave;
    if (v >= kN) return;

    int e0 = rp[v], e1 = rp[v + 1];
    float wt[11];
    #pragma unroll
    for (int t = 0; t < 11; t++) wt[t] = 0.f;
    for (int base = e0; base < e1; base += 64) {
        int e = base + lane;
        int xs = 15; float ds = 0.f;
        if (e < e1) {
            int2 t = xdb[ci[e]];
            xs = t.x; ds = __int_as_float(t.y);
        }
        #pragma unroll
        for (int t = 0; t < 11; t++) wt[t] += (xs == t) ? ds : 0.f;
    }
    #pragma unroll
    for (int t = 0; t < 11; t++) {
        float s = wt[t];
        #pragma unroll
        for (int o = 1; o < 64; o <<= 1) s += __shfl_xor(s, o);
        wt[t] = s;
    }

    int c = lane * 4;
    float4 bia = *(const float4*)(bias + c);
    int2 xv = xdb[v];
    float dv = __int_as_float(xv.y);
    float4 m = *(const float4*)(M11 + xv.x * kGH + c);
    float4 acc = make_float4(dv * m.x, dv * m.y, dv * m.z, dv * m.w);
    #pragma unroll
    for (int t = 0; t < 11; t++) {
        float w = wt[t];
        float4 mt = *(const float4*)(M11 + t * kGH + c);
        acc.x += w * mt.x; acc.y += w * mt.y;
        acc.z += w * mt.z; acc.w += w * mt.w;
    }
    half4v o;
    o[0] = (_Float16)fmaxf(dv * acc.x + bia.x, 0.f);
    o[1] = (_Float16)fmaxf(dv * acc.y + bia.y, 0.f);
    o[2] = (_Float16)fmaxf(dv * acc.z + bia.z, 0.f);
    o[3] = (_Float16)fmaxf(dv * acc.w + bia.w, 0.f);
    *(half4v*)(ob + (size_t)v * kGH + c) = o;
}

// ---------------------------------------------------------------------------
// Conv2 GEMM via MFMA f16, LDS-tiled: hs = dinv ⊙ (h2 @ W2)
// BM=128, BN=128, BK=64 (R9-measured config). 4 waves (2x2); wave = 64x64.
// ---------------------------------------------------------------------------
__launch_bounds__(256)
__global__ void gemm2_mfma_kernel(const _Float16* __restrict__ A,
                                  const _Float16* __restrict__ Bt,
                                  const float* __restrict__ dinv,
                                  _Float16* __restrict__ C) {
    __shared__ _Float16 As[128][72];
    __shared__ _Float16 Bs[128][72];

    int side = blockIdx.z;
    const _Float16* Ab = A + (size_t)side * kN * kGH;
    const float* db = dinv + (size_t)side * kN;
    _Float16* Cb = C + (size_t)side * kN * kGH;

    int tid = threadIdx.x;
    int wave = tid >> 6, lane = tid & 63;
    int quad = lane >> 4, r = lane & 15;
    int wm = wave >> 1, wn = wave & 1;
    int row0 = blockIdx.x * 128;
    int col0 = blockIdx.y * 128;

    floatx4 acc[4][4];
    #pragma unroll
    for (int i = 0; i < 4; i++)
        #pragma unroll
        for (int j = 0; j < 4; j++) acc[i][j] = (floatx4){0.f, 0.f, 0.f, 0.f};

    for (int k0 = 0; k0 < kGH; k0 += 64) {
        #pragma unroll
        for (int u = 0; u < 4; u++) {
            int idx = tid + u * 256;           // 0..1023
            int row = idx >> 3;                // 0..127
            int seg = (idx & 7) * 8;           // 0..56
            int gr = row0 + row;
            if (gr >= kN) gr = kN - 1;
            *(half8v*)&As[row][seg] = *(const half8v*)(Ab + (size_t)gr * kGH + k0 + seg);
            *(half8v*)&Bs[row][seg] = *(const half8v*)(Bt + (size_t)(col0 + row) * kGH + k0 + seg);
        }
        __syncthreads();
        #pragma unroll
        for (int ks = 0; ks < 2; ks++) {
            half8v af[4], bf[4];
            #pragma unroll
            for (int mt = 0; mt < 4; mt++)
                af[mt] = *(const half8v*)&As[wm * 64 + mt * 16 + r][ks * 32 + quad * 8];
            #pragma unroll
            for (int nt = 0; nt < 4; nt++)
                bf[nt] = *(const half8v*)&Bs[wn * 64 + nt * 16 + r][ks * 32 + quad * 8];
            #pragma unroll
            for (int mt = 0; mt < 4; mt++)
                #pragma unroll
                for (int nt = 0; nt < 4; nt++)
                    acc[mt][nt] = __builtin_amdgcn_mfma_f32_16x16x32_f16(af[mt], bf[nt],
                                                                         acc[mt][nt], 0, 0, 0);
        }
        __syncthreads();
    }

    // Epilogue: C/D layout col = r, row = quad*4 + i
    #pragma unroll
    for (int mt = 0; mt < 4; mt++) {
        #pragma unroll
        for (int i = 0; i < 4; i++) {
            int grow = row0 + wm * 64 + mt * 16 + quad * 4 + i;
            if (grow >= kN) continue;
            float rs = db[grow];
            #pragma unroll
            for (int nt = 0; nt < 4; nt++) {
                int gcol = col0 + wn * 64 + nt * 16 + r;
                Cb[(size_t)grow * kGH + gcol] = (_Float16)(acc[mt][nt][i] * rs);
            }
        }
    }
}

// ---------------------------------------------------------------------------
// Conv2 aggregate: h4[v] = relu(dinv[v]*(hs[v] + sum_s hs[s]) + b2)  (hs fp16)
// Near the combined cache+HBM gather roofline; 16-wide ILP.
// ---------------------------------------------------------------------------
__global__ void aggregate2_kernel(const _Float16* __restrict__ hs, const float* __restrict__ dinv,
                                  const int* __restrict__ row_ptr, const int* __restrict__ col_idx,
                                  const float* __restrict__ bias, _Float16* __restrict__ out) {
    int side = blockIdx.y;
    const _Float16* hb = hs + (size_t)side * kN * kGH;
    const float* dv_ = dinv + side * kN;
    const int* rp = row_ptr + side * (kN + 1);
    const int* ci = col_idx + (size_t)side * kE;
    _Float16* ob = out + (size_t)side * kN * kGH;

    int wave = threadIdx.x >> 6;
    int lane = threadIdx.x & 63;
    int v = blockIdx.x * 4 + wave;
    if (v >= kN) return;
    int c = lane * 4;
    float4 bia = *(const float4*)(bias + c);
    float dv = dv_[v];
    half4v hv = *(const half4v*)(hb + (size_t)v * kGH + c);   // self-loop term
    float a0 = (float)hv[0], a1 = (float)hv[1], a2 = (float)hv[2], a3 = (float)hv[3];
    int e0 = rp[v], e1 = rp[v + 1];
    for (int base = e0; base < e1; base += 64) {
        int cnt = min(64, e1 - base);
        int idxl = (base + lane < e1) ? ci[base + lane] : 0;
        int j = 0;
        for (; j + 16 <= cnt; j += 16) {
            half4v h[16];
            #pragma unroll
            for (int u = 0; u < 16; u++)
                h[u] = *(const half4v*)(hb + (size_t)__shfl(idxl, j + u) * kGH + c);
            #pragma unroll
            for (int u = 0; u < 16; u++) {
                a0 += (float)h[u][0]; a1 += (float)h[u][1];
                a2 += (float)h[u][2]; a3 += (float)h[u][3];
            }
        }
        for (; j + 8 <= cnt; j += 8) {
            half4v h[8];
            #pragma unroll
            for (int u = 0; u < 8; u++)
                h[u] = *(const half4v*)(hb + (size_t)__shfl(idxl, j + u) * kGH + c);
            #pragma unroll
            for (int u = 0; u < 8; u++) {
                a0 += (float)h[u][0]; a1 += (float)h[u][1];
                a2 += (float)h[u][2]; a3 += (float)h[u][3];
            }
        }
        for (; j < cnt; j++) {
            half4v h = *(const half4v*)(hb + (size_t)__shfl(idxl, j) * kGH + c);
            a0 += (float)h[0]; a1 += (float)h[1]; a2 += (float)h[2]; a3 += (float)h[3];
        }
    }
    half4v o;
    o[0] = (_Float16)fmaxf(dv * a0 + bia.x, 0.f);
    o[1] = (_Float16)fmaxf(dv * a1 + bia.y, 0.f);
    o[2] = (_Float16)fmaxf(dv * a2 + bia.z, 0.f);
    o[3] = (_Float16)fmaxf(dv * a3 + bia.w, 0.f);
    *(half4v*)(ob + (size_t)v * kGH + c) = o;
}

// ---------------------------------------------------------------------------
// Fused mean-pool + fc:  gfc[g] = mean_{v in g}(h4[v]) @ fcW + fcb
// ---------------------------------------------------------------------------
__global__ void poolfc_kernel(const _Float16* __restrict__ h,
                              const int* __restrict__ batch1, const int* __restrict__ batch2,
                              const float* __restrict__ fcW, const float* __restrict__ fcb,
                              float* __restrict__ gfc) {
    int side = blockIdx.y;
    const _Float16* hb = h + (size_t)side * kN * kGH;
    const int* batch = side ? batch2 : batch1;
    int g = blockIdx.x;
    int lo = 0, hi = kN;
    while (lo < hi) { int mid = (lo + hi) >> 1; if (batch[mid] < g) lo = mid + 1; else hi = mid; }
    int start = lo;
    lo = start; hi = kN;
    while (lo < hi) { int mid = (lo + hi) >> 1; if (batch[mid] < g + 1) lo = mid + 1; else hi = mid; }
    int end = lo;
    int c = threadIdx.x;  // 256
    float s = 0.f;
    for (int v = start; v < end; v++) s += (float)hb[(size_t)v * kGH + c];
    __shared__ float ps[256];
    ps[c] = s / fmaxf((float)(end - start), 1.0f);
    __syncthreads();
    float acc = fcb[c];
    #pragma unroll 4
    for (int k = 0; k < kGH; k++) acc += ps[k] * fcW[(size_t)k * kGH + c];
    gfc[(size_t)(side * kG + g) * kGH + c] = acc;
}

// ---------------------------------------------------------------------------
// Generic tiled fp32 GEMM (tail layers): C = (A@B) [+bias] [relu]
// ---------------------------------------------------------------------------
__launch_bounds__(256)
__global__ void gemm_kernel(const float* __restrict__ A, const float* __restrict__ B,
                            float* __restrict__ C, int M, int N, int K,
                            const float* __restrict__ bias, int relu) {
    __shared__ float As[16][64];
    __shared__ float Bs[16][64];
    int tid = threadIdx.x;
    int tx = tid & 15, ty = tid >> 4;
    int row0 = blockIdx.y * 64, col0 = blockIdx.x * 64;
    float acc[4][4] = {};
    for (int k0 = 0; k0 < K; k0 += 16) {
        {
            int r = tid >> 2, seg = tid & 3;
            int gr = row0 + r;
            float4 v = make_float4(0.f, 0.f, 0.f, 0.f);
            if (gr < M) v = *(const float4*)(A + (size_t)gr * K + k0 + seg * 4);
            As[seg * 4 + 0][r] = v.x; As[seg * 4 + 1][r] = v.y;
            As[seg * 4 + 2][r] = v.z; As[seg * 4 + 3][r] = v.w;
        }
        {
            int kr = tid >> 4, c4 = (tid & 15) * 4;
            float4 v = *(const float4*)(B + (size_t)(k0 + kr) * N + col0 + c4);
            *(float4*)&Bs[kr][c4] = v;
        }
        __syncthreads();
        #pragma unroll
        for (int k = 0; k < 16; k++) {
            float a[4], b[4];
            #pragma unroll
            for (int i = 0; i < 4; i++) a[i] = As[k][ty * 4 + i];
            #pragma unroll
            for (int j = 0; j < 4; j++) b[j] = Bs[k][tx * 4 + j];
            #pragma unroll
            for (int i = 0; i < 4; i++)
                #pragma unroll
                for (int j = 0; j < 4; j++)
                    acc[i][j] += a[i] * b[j];
        }
        __syncthreads();
    }
    #pragma unroll
    for (int i = 0; i < 4; i++) {
        int gr = row0 + ty * 4 + i;
        if (gr >= M) continue;
        #pragma unroll
        for (int j = 0; j < 4; j++) {
            int gc = col0 + tx * 4 + j;
            float v = acc[i][j];
            if (bias) v += bias[gc];
            if (relu) v = fmaxf(v, 0.f);
            C[(size_t)gr * N + gc] = v;
        }
    }
}

// ---------------------------------------------------------------------------
// eW1 GEMM with fused entity gather+relu on the A-load.
// ---------------------------------------------------------------------------
__launch_bounds__(256)
__global__ void gemm_entgather_kernel(const float* __restrict__ emb,
                                      const int* __restrict__ ent1, const int* __restrict__ ent2,
                                      const float* __restrict__ B, float* __restrict__ C,
                                      int N, const float* __restrict__ bias) {
    __shared__ float As[16][64];
    __shared__ float Bs[16][64];
    int tid = threadIdx.x;
    int tx = tid & 15, ty = tid >> 4;
    int row0 = blockIdx.y * 64, col0 = blockIdx.x * 64;
    float acc[4][4] = {};
    for (int k0 = 0; k0 < kEMB; k0 += 16) {
        {
            int r = tid >> 2, seg = tid & 3;
            int gr = row0 + r;                 // < 2G always
            int idx = (gr < kG) ? ent1[gr] : ent2[gr - kG];
            float4 v = *(const float4*)(emb + (size_t)idx * kEMB + k0 + seg * 4);
            As[seg * 4 + 0][r] = fmaxf(v.x, 0.f); As[seg * 4 + 1][r] = fmaxf(v.y, 0.f);
            As[seg * 4 + 2][r] = fmaxf(v.z, 0.f); As[seg * 4 + 3][r] = fmaxf(v.w, 0.f);
        }
        {
            int kr = tid >> 4, c4 = (tid & 15) * 4;
            float4 v = *(const float4*)(B + (size_t)(k0 + kr) * N + col0 + c4);
            *(float4*)&Bs[kr][c4] = v;
        }
        __syncthreads();
        #pragma unroll
        for (int k = 0; k < 16; k++) {
            float a[4], b[4];
            #pragma unroll
            for (int i = 0; i < 4; i++) a[i] = As[k][ty * 4 + i];
            #pragma unroll
            for (int j = 0; j < 4; j++) b[j] = Bs[k][tx * 4 + j];
            #pragma unroll
            for (int i = 0; i < 4; i++)
                #pragma unroll
                for (int j = 0; j < 4; j++)
                    acc[i][j] += a[i] * b[j];
        }
        __syncthreads();
    }
    #pragma unroll
    for (int i = 0; i < 4; i++) {
        int gr = row0 + ty * 4 + i;
        #pragma unroll
        for (int j = 0; j < 4; j++) {
            int gc = col0 + tx * 4 + j;
            C[(size_t)gr * N + gc] = fmaxf(acc[i][j] + bias[gc], 0.f);
        }
    }
}

// ---------------------------------------------------------------------------
// dW1 GEMM with fused egs computation on the A-load.
// ---------------------------------------------------------------------------
__launch_bounds__(256)
__global__ void gemm_egs_kernel(const float* __restrict__ gfc, const float* __restrict__ ento,
                                const float* __restrict__ B, float* __restrict__ C,
                                int N, const float* __restrict__ bias) {
    __shared__ float As[16][64];
    __shared__ float Bs[16][64];
    int tid = threadIdx.x;
    int tx = tid & 15, ty = tid >> 4;
    int row0 = blockIdx.y * 64, col0 = blockIdx.x * 64;
    float acc[4][4] = {};
    for (int k0 = 0; k0 < kHID; k0 += 16) {
        {
            int r = tid >> 2, seg = tid & 3;
            int gr = row0 + r;                 // < G always
            int k = k0 + seg * 4;
            float4 va, vb;
            if (k < kGH) {
                va = *(const float4*)(gfc + (size_t)gr * kGH + k);
                vb = *(const float4*)(gfc + (size_t)(gr + kG) * kGH + k);
            } else {
                va = *(const float4*)(ento + (size_t)gr * kEH + k - kGH);
                vb = *(const float4*)(ento + (size_t)(gr + kG) * kEH + k - kGH);
            }
            As[seg * 4 + 0][r] = fmaxf(va.x + vb.x, 0.f);
            As[seg * 4 + 1][r] = fmaxf(va.y + vb.y, 0.f);
            As[seg * 4 + 2][r] = fmaxf(va.z + vb.z, 0.f);
            As[seg * 4 + 3][r] = fmaxf(va.w + vb.w, 0.f);
        }
        {
            int kr = tid >> 4, c4 = (tid & 15) * 4;
            float4 v = *(const float4*)(B + (size_t)(k0 + kr) * N + col0 + c4);
            *(float4*)&Bs[kr][c4] = v;
        }
        __syncthreads();
        #pragma unroll
        for (int k = 0; k < 16; k++) {
            float a[4], b[4];
            #pragma unroll
            for (int i = 0; i < 4; i++) a[i] = As[k][ty * 4 + i];
            #pragma unroll
            for (int j = 0; j < 4; j++) b[j] = Bs[k][tx * 4 + j];
            #pragma unroll
            for (int i = 0; i < 4; i++)
                #pragma unroll
                for (int j = 0; j < 4; j++)
                    acc[i][j] += a[i] * b[j];
        }
        __syncthreads();
    }
    #pragma unroll
    for (int i = 0; i < 4; i++) {
        int gr = row0 + ty * 4 + i;
        #pragma unroll
        for (int j = 0; j < 4; j++) {
            int gc = col0 + tx * 4 + j;
            C[(size_t)gr * N + gc] = fmaxf(acc[i][j] + bias[gc], 0.f);
        }
    }
}

// ---------------------------------------------------------------------------
// Host launch
// ---------------------------------------------------------------------------
static inline char* carve(char*& p, size_t bytes) {
    char* r = p;
    p += (bytes + 255) & ~(size_t)255;
    return r;
}

extern "C" void kernel_launch(void* const* d_in, const int* in_sizes, int n_in,
                              void* d_out, int out_size, void* d_ws, size_t ws_size,
                              hipStream_t stream) {
    const int*   x1       = (const int*)d_in[0];
    const int*   ei1      = (const int*)d_in[1];
    const int*   ent1     = (const int*)d_in[2];
    const int*   batch1   = (const int*)d_in[3];
    const int*   x2       = (const int*)d_in[4];
    const int*   ei2      = (const int*)d_in[5];
    const int*   ent2     = (const int*)d_in[6];
    const int*   batch2   = (const int*)d_in[7];
    const float* atom_emb = (const float*)d_in[8];
    const float* gW1      = (const float*)d_in[9];
    const float* gb1      = (const float*)d_in[10];
    const float* gW2      = (const float*)d_in[11];
    const float* gb2      = (const float*)d_in[12];
    const float* fcW      = (const float*)d_in[13];
    const float* fcb      = (const float*)d_in[14];
    const float* ent_emb  = (const float*)d_in[15];
    const float* eW1      = (const float*)d_in[16];
    const float* eb1      = (const float*)d_in[17];
    const float* eW2      = (const float*)d_in[18];
    const float* eb2      = (const float*)d_in[19];
    const float* dW1      = (const float*)d_in[20];
    const float* db1      = (const float*)d_in[21];
    const float* dW2      = (const float*)d_in[22];
    const float* db2      = (const float*)d_in[23];
    const float* dW3      = (const float*)d_in[24];
    const float* db3      = (const float*)d_in[25];
    float* out = (float*)d_out;

    // Workspace carve; counts (padded) is the only zeroed span.
    char* p = (char*)d_ws;
    _Float16* h2_h   = (_Float16*)carve(p, (size_t)2 * kN * kGH * 2);  // also h4
    _Float16* hs_h   = (_Float16*)carve(p, (size_t)2 * kN * kGH * 2);
    int*   col_idx = (int*)  carve(p, (size_t)2 * kE * 4);
    int*   rankb   = (int*)  carve(p, (size_t)2 * kE * 4);
    int*   row_ptr = (int*)  carve(p, (size_t)2 * (kN + 1) * 4);
    int*   counts  = (int*)  carve(p, (size_t)2 * kN * kCS * 4);   // 1 counter / 64B line
    float* dinv    = (float*)carve(p, (size_t)2 * kN * 4);
    int2*  xd      = (int2*) carve(p, (size_t)2 * kN * 8);
    int*   bsum    = (int*)  carve(p, (size_t)2 * kNB * 4);
    int*   boff    = (int*)  carve(p, (size_t)2 * kNB * 4);
    float* M11     = (float*)carve(p, 11 * kGH * 4);
    _Float16* w2t  = (_Float16*)carve(p, (size_t)kGH * kGH * 2);
    float* gfc     = (float*)carve(p, (size_t)2 * kG * kGH * 4);
    float* etmp    = (float*)carve(p, (size_t)2 * kG * kEH * 4);
    float* ento    = (float*)carve(p, (size_t)2 * kG * kEH * 4);
    float* dh1     = (float*)carve(p, (size_t)kG * kHID * 4);
    float* dh2     = (float*)carve(p, (size_t)kG * kHID * 4);

    // --- Graph structure + conv1 (kernel boundaries = safe grid barriers) ---
    hipMemsetAsync(counts, 0, (size_t)2 * kN * kCS * 4, stream);
    prep_kernel<<<267, 256, 0, stream>>>(atom_emb, gW1, gW2, M11, w2t);
    rank_kernel<<<dim3(kE / 256, 2), 256, 0, stream>>>(ei1, ei2, counts, rankb);
    bsum_kernel<<<dim3(kNB, 2), 256, 0, stream>>>(counts, bsum);
    bscan_kernel<<<2, 256, 0, stream>>>(bsum, boff);
    scanf_kernel<<<dim3(kNB, 2), 256, 0, stream>>>(counts, boff, row_ptr, dinv, xd, x1, x2);
    scatter_kernel<<<dim3(kE / 256, 2), 256, 0, stream>>>(ei1, ei2, row_ptr, rankb, col_idx);
    conv1_combine_kernel<<<dim3((kN + 3) / 4, 2), 256, 0, stream>>>(xd, row_ptr, col_idx,
                                                                    M11, gb1, h2_h);

    // --- Conv2 GEMM (MFMA f16, BN=128): hs = dinv ⊙ (h2 @ W2) ---
    gemm2_mfma_kernel<<<dim3((kN + 127) / 128, kGH / 128, 2), 256, 0, stream>>>(h2_h, w2t,
                                                                                dinv, hs_h);
    // --- Conv2 aggregate -> h4 (reuses h2 buffer) ---
    aggregate2_kernel<<<dim3((kN + 3) / 4, 2), 256, 0, stream>>>(hs_h, dinv, row_ptr, col_idx,
                                                                 gb2, h2_h);
    // --- Fused mean-pool + fc -> gfc [2G, GH] ---
    poolfc_kernel<<<dim3(kG, 2), 256, 0, stream>>>(h2_h, batch1, batch2, fcW, fcb, gfc);

    // --- Entity encoders (gather+relu fused into eW1) ---
    gemm_entgather_kernel<<<dim3(kEH / 64, 2 * kG / 64), 256, 0, stream>>>(ent_emb, ent1, ent2,
                                                                           eW1, etmp, kEH, eb1);
    gemm_kernel<<<dim3(kEH / 64, 2 * kG / 64), 256, 0, stream>>>(etmp, eW2, ento,
                                                                 2 * kG, kEH, kEH, eb2, 1);
    // --- Decoder (egs fused into dW1) ---
    gemm_egs_kernel<<<dim3(kHID / 64, kG / 64), 256, 0, stream>>>(gfc, ento, dW1, dh1,
                                                                  kHID, db1);
    gemm_kernel<<<dim3(kHID / 64, kG / 64), 256, 0, stream>>>(dh1, dW2, dh2,
                                                              kG, kHID, kHID, db2, 1);
    gemm_kernel<<<dim3(kOUT / 64, kG / 64), 256, 0, stream>>>(dh2, dW3, out,
                                                              kG, kOUT, kHID, db3, 0);
}

// Round 13
// 673.305 us; speedup vs baseline: 1.0616x; 1.0085x over previous
//
#include <hip/hip_runtime.h>
#include <hip/hip_fp16.h>

// Problem constants
static constexpr int kN = 50000;      // nodes per side
static constexpr int kE = 800000;     // edges per side
static constexpr int kG = 1024;       // graphs per batch
static constexpr int kEMB = 128;
static constexpr int kGH = 256;
static constexpr int kEH = 256;
static constexpr int kOUT = 128;
static constexpr int kHID = 512;
static constexpr int kNB = (kN + 255) / 256;   // 196 scan chunks per side

typedef __attribute__((ext_vector_type(8))) _Float16 half8v;
typedef __attribute__((ext_vector_type(4))) _Float16 half4v;
typedef __attribute__((ext_vector_type(4))) float floatx4;

// NOTE (R6): cross-XCD plain-data handoff through grid.sync() gave stale reads.
// Phase boundaries are separate dispatches.
// NOTE (R7): device atomics execute memory-side; each dirties a 64B line.
// NOTE (R12): atomic floor is OP-COUNT (~21 ops/ns) — line padding is neutral.
// NOTE (R8): rank trick — counting atomic's return value = edge's rank in dst.
// NOTE (R10): lookback scan regressed (serial polling); BN=256 gemm2 regressed
// (VGPR/occupancy). NOTE (R11): heterogeneous role-merged grids regressed.
// Measured floors: aggregate2 110us (random-gather roofline), rank ~76us
// (atomic op floor), scatter ~55us (random line-RMW stores).

// ---------------------------------------------------------------------------
// prep: w2t = fp16(gW2^T) (blocks 0..255), M11 = atom_emb@gW1 (blocks 256..266)
// ---------------------------------------------------------------------------
__global__ void prep_kernel(const float* __restrict__ atom_emb, const float* __restrict__ gW1,
                            const float* __restrict__ gW2,
                            float* __restrict__ M11, _Float16* __restrict__ w2t) {
    int i = blockIdx.x * 256 + threadIdx.x;
    if (blockIdx.x < 256) {
        int k = i >> 8, n = i & 255;
        w2t[(size_t)n * kGH + k] = (_Float16)gW2[(size_t)k * kGH + n];
    } else {
        int j = i - 65536;
        if (j < 11 * kGH) {
            int r = j >> 8, c = j & 255;
            float s = 0.f;
            for (int k = 0; k < kEMB; k++) s += atom_emb[r * kEMB + k] * gW1[k * kGH + c];
            M11[j] = s;
        }
    }
}

// ---------------------------------------------------------------------------
// Rank pass: one returning atomic per edge (op-count floor, R12-measured).
// ---------------------------------------------------------------------------
__global__ void rank_kernel(const int* __restrict__ ei1, const int* __restrict__ ei2,
                            int* __restrict__ counts, int* __restrict__ rankb) {
    int side = blockIdx.y;
    const int* dst = (side ? ei2 : ei1) + kE;
    int i = blockIdx.x * blockDim.x + threadIdx.x;
    if (i >= kE) return;
    rankb[(size_t)side * kE + i] = atomicAdd(&counts[side * kN + dst[i]], 1);
}

// Per-chunk sums (196 chunks per side)
__global__ void bsum_kernel(const int* __restrict__ counts, int* __restrict__ bsum) {
    int side = blockIdx.y;
    const int* c = counts + side * kN;
    int i = blockIdx.x * 256 + threadIdx.x;
    int v = (i < kN) ? c[i] : 0;
    #pragma unroll
    for (int o = 32; o; o >>= 1) v += __shfl_down(v, o);
    __shared__ int ws[4];
    if ((threadIdx.x & 63) == 0) ws[threadIdx.x >> 6] = v;
    __syncthreads();
    if (threadIdx.x == 0) bsum[side * kNB + blockIdx.x] = ws[0] + ws[1] + ws[2] + ws[3];
}

// Exclusive scan of the chunk sums (one block per side)
__global__ void bscan_kernel(const int* __restrict__ bsum, int* __restrict__ boff) {
    int side = blockIdx.x;
    __shared__ int s[256];
    int t = threadIdx.x;
    int v = (t < kNB) ? bsum[side * kNB + t] : 0;
    s[t] = v;
    __syncthreads();
    for (int o = 1; o < 256; o <<= 1) {
        int u = (t >= o) ? s[t - o] : 0;
        __syncthreads();
        s[t] += u;
        __syncthreads();
    }
    if (t < kNB) boff[side * kNB + t] = s[t] - v;   // exclusive
}

// Final: local inclusive scan per chunk + chunk offset -> row_ptr.
// Fused: dinv = rsqrt(deg+1) and xd[v] = (x[v], bits(dinv[v])).
__global__ void scanf_kernel(const int* __restrict__ counts, const int* __restrict__ boff,
                             int* __restrict__ row_ptr, float* __restrict__ dinv,
                             int2* __restrict__ xd,
                             const int* __restrict__ x1, const int* __restrict__ x2) {
    int side = blockIdx.y;
    const int* c = counts + side * kN;
    int* rp = row_ptr + side * (kN + 1);
    int t = threadIdx.x;
    int i = blockIdx.x * 256 + t;
    __shared__ int s[256];
    int v = (i < kN) ? c[i] : 0;
    s[t] = v;
    __syncthreads();
    for (int o = 1; o < 256; o <<= 1) {
        int u = (t >= o) ? s[t - o] : 0;
        __syncthreads();
        s[t] += u;
        __syncthreads();
    }
    if (i < kN) {
        rp[i + 1] = boff[side * kNB + blockIdx.x] + s[t];
        float dv = rsqrtf((float)(v + 1));           // +1 self-loop
        dinv[side * kN + i] = dv;
        const int* x = side ? x2 : x1;
        xd[side * kN + i] = make_int2(x[i], __float_as_int(dv));
    }
    if (i == 0) rp[0] = 0;
}

// ---------------------------------------------------------------------------
// CSR scatter: plain stores, zero atomics (pos = row_ptr[d] + rank[e]).
// ---------------------------------------------------------------------------
__global__ void scatter_kernel(const int* __restrict__ ei1, const int* __restrict__ ei2,
                               const int* __restrict__ row_ptr, const int* __restrict__ rank,
                               int* __restrict__ col_idx) {
    int side = blockIdx.y;
    const int* ei = side ? ei2 : ei1;
    const int* rp = row_ptr + side * (kN + 1);
    int i = blockIdx.x * blockDim.x + threadIdx.x;
    if (i >= kE) return;
    int s = ei[i];           // src
    int d = ei[kE + i];      // dst
    int pos = rp[d] + rank[(size_t)side * kE + i];
    col_idx[(size_t)side * kE + pos] = s;
}

// ---------------------------------------------------------------------------
// Conv1 combine with in-kernel 11-bin histogram (zero atomics).
// h2[v] = relu(dv*(dv*M11[x[v]] + sum_t w[t]*M11[t]) + b1)
// ---------------------------------------------------------------------------
__global__ void conv1_combine_kernel(const int2* __restrict__ xd,
                                     const int* __restrict__ row_ptr,
                                     const int* __restrict__ col_idx,
                                     const float* __restrict__ M11,
                                     const float* __restrict__ bias,
                                     _Float16* __restrict__ out) {
    int side = blockIdx.y;
    const int2* xdb = xd + (size_t)side * kN;
    const int* rp = row_ptr + side * (kN + 1);
    const int* ci = col_idx + (size_t)side * kE;
    _Float16* ob = out + (size_t)side * kN * kGH;

    int wave = threadIdx.x >> 6;
    int lane = threadIdx.x & 63;
    int v = blockIdx.x * 4 + wave;
    if (v >= kN) return;

    int e0 = rp[v], e1 = rp[v + 1];
    float wt[11];
    #pragma unroll
    for (int t = 0; t < 11; t++) wt[t] = 0.f;
    for (int base = e0; base < e1; base += 64) {
        int e = base + lane;
        int xs = 15; float ds = 0.f;
        if (e < e1) {
            int2 t = xdb[ci[e]];
            xs = t.x; ds = __int_as_float(t.y);
        }
        #pragma unroll
        for (int t = 0; t < 11; t++) wt[t] += (xs == t) ? ds : 0.f;
    }
    #pragma unroll
    for (int t = 0; t < 11; t++) {
        float s = wt[t];
        #pragma unroll
        for (int o = 1; o < 64; o <<= 1) s += __shfl_xor(s, o);
        wt[t] = s;
    }

    int c = lane * 4;
    float4 bia = *(const float4*)(bias + c);
    int2 xv = xdb[v];
    float dv = __int_as_float(xv.y);
    float4 m = *(const float4*)(M11 + xv.x * kGH + c);
    float4 acc = make_float4(dv * m.x, dv * m.y, dv * m.z, dv * m.w);
    #pragma unroll
    for (int t = 0; t < 11; t++) {
        float w = wt[t];
        float4 mt = *(const float4*)(M11 + t * kGH + c);
        acc.x += w * mt.x; acc.y += w * mt.y;
        acc.z += w * mt.z; acc.w += w * mt.w;
    }
    half4v o;
    o[0] = (_Float16)fmaxf(dv * acc.x + bia.x, 0.f);
    o[1] = (_Float16)fmaxf(dv * acc.y + bia.y, 0.f);
    o[2] = (_Float16)fmaxf(dv * acc.z + bia.z, 0.f);
    o[3] = (_Float16)fmaxf(dv * acc.w + bia.w, 0.f);
    *(half4v*)(ob + (size_t)v * kGH + c) = o;
}

// ---------------------------------------------------------------------------
// Conv2 GEMM via MFMA f16, LDS-tiled: hs = dinv ⊙ (h2 @ W2)
// BM=128, BN=128, BK=64 (R9-measured config). 4 waves (2x2); wave = 64x64.
// ---------------------------------------------------------------------------
__launch_bounds__(256)
__global__ void gemm2_mfma_kernel(const _Float16* __restrict__ A,
                                  const _Float16* __restrict__ Bt,
                                  const float* __restrict__ dinv,
                                  _Float16* __restrict__ C) {
    __shared__ _Float16 As[128][72];
    __shared__ _Float16 Bs[128][72];

    int side = blockIdx.z;
    const _Float16* Ab = A + (size_t)side * kN * kGH;
    const float* db = dinv + (size_t)side * kN;
    _Float16* Cb = C + (size_t)side * kN * kGH;

    int tid = threadIdx.x;
    int wave = tid >> 6, lane = tid & 63;
    int quad = lane >> 4, r = lane & 15;
    int wm = wave >> 1, wn = wave & 1;
    int row0 = blockIdx.x * 128;
    int col0 = blockIdx.y * 128;

    floatx4 acc[4][4];
    #pragma unroll
    for (int i = 0; i < 4; i++)
        #pragma unroll
        for (int j = 0; j < 4; j++) acc[i][j] = (floatx4){0.f, 0.f, 0.f, 0.f};

    for (int k0 = 0; k0 < kGH; k0 += 64) {
        #pragma unroll
        for (int u = 0; u < 4; u++) {
            int idx = tid + u * 256;           // 0..1023
            int row = idx >> 3;                // 0..127
            int seg = (idx & 7) * 8;           // 0..56
            int gr = row0 + row;
            if (gr >= kN) gr = kN - 1;
            *(half8v*)&As[row][seg] = *(const half8v*)(Ab + (size_t)gr * kGH + k0 + seg);
            *(half8v*)&Bs[row][seg] = *(const half8v*)(Bt + (size_t)(col0 + row) * kGH + k0 + seg);
        }
        __syncthreads();
        #pragma unroll
        for (int ks = 0; ks < 2; ks++) {
            half8v af[4], bf[4];
            #pragma unroll
            for (int mt = 0; mt < 4; mt++)
                af[mt] = *(const half8v*)&As[wm * 64 + mt * 16 + r][ks * 32 + quad * 8];
            #pragma unroll
            for (int nt = 0; nt < 4; nt++)
                bf[nt] = *(const half8v*)&Bs[wn * 64 + nt * 16 + r][ks * 32 + quad * 8];
            #pragma unroll
            for (int mt = 0; mt < 4; mt++)
                #pragma unroll
                for (int nt = 0; nt < 4; nt++)
                    acc[mt][nt] = __builtin_amdgcn_mfma_f32_16x16x32_f16(af[mt], bf[nt],
                                                                         acc[mt][nt], 0, 0, 0);
        }
        __syncthreads();
    }

    // Epilogue: C/D layout col = r, row = quad*4 + i
    #pragma unroll
    for (int mt = 0; mt < 4; mt++) {
        #pragma unroll
        for (int i = 0; i < 4; i++) {
            int grow = row0 + wm * 64 + mt * 16 + quad * 4 + i;
            if (grow >= kN) continue;
            float rs = db[grow];
            #pragma unroll
            for (int nt = 0; nt < 4; nt++) {
                int gcol = col0 + wn * 64 + nt * 16 + r;
                Cb[(size_t)grow * kGH + gcol] = (_Float16)(acc[mt][nt][i] * rs);
            }
        }
    }
}

// ---------------------------------------------------------------------------
// Conv2 aggregate: h4[v] = relu(dinv[v]*(hs[v] + sum_s hs[s]) + b2)  (hs fp16)
// At the combined cache+HBM random-gather roofline (R5..R12-measured).
// ---------------------------------------------------------------------------
__global__ void aggregate2_kernel(const _Float16* __restrict__ hs, const float* __restrict__ dinv,
                                  const int* __restrict__ row_ptr, const int* __restrict__ col_idx,
                                  const float* __restrict__ bias, _Float16* __restrict__ out) {
    int side = blockIdx.y;
    const _Float16* hb = hs + (size_t)side * kN * kGH;
    const float* dv_ = dinv + side * kN;
    const int* rp = row_ptr + side * (kN + 1);
    const int* ci = col_idx + (size_t)side * kE;
    _Float16* ob = out + (size_t)side * kN * kGH;

    int wave = threadIdx.x >> 6;
    int lane = threadIdx.x & 63;
    int v = blockIdx.x * 4 + wave;
    if (v >= kN) return;
    int c = lane * 4;
    float4 bia = *(const float4*)(bias + c);
    float dv = dv_[v];
    half4v hv = *(const half4v*)(hb + (size_t)v * kGH + c);   // self-loop term
    float a0 = (float)hv[0], a1 = (float)hv[1], a2 = (float)hv[2], a3 = (float)hv[3];
    int e0 = rp[v], e1 = rp[v + 1];
    for (int base = e0; base < e1; base += 64) {
        int cnt = min(64, e1 - base);
        int idxl = (base + lane < e1) ? ci[base + lane] : 0;
        int j = 0;
        for (; j + 16 <= cnt; j += 16) {
            half4v h[16];
            #pragma unroll
            for (int u = 0; u < 16; u++)
                h[u] = *(const half4v*)(hb + (size_t)__shfl(idxl, j + u) * kGH + c);
            #pragma unroll
            for (int u = 0; u < 16; u++) {
                a0 += (float)h[u][0]; a1 += (float)h[u][1];
                a2 += (float)h[u][2]; a3 += (float)h[u][3];
            }
        }
        for (; j + 8 <= cnt; j += 8) {
            half4v h[8];
            #pragma unroll
            for (int u = 0; u < 8; u++)
                h[u] = *(const half4v*)(hb + (size_t)__shfl(idxl, j + u) * kGH + c);
            #pragma unroll
            for (int u = 0; u < 8; u++) {
                a0 += (float)h[u][0]; a1 += (float)h[u][1];
                a2 += (float)h[u][2]; a3 += (float)h[u][3];
            }
        }
        for (; j < cnt; j++) {
            half4v h = *(const half4v*)(hb + (size_t)__shfl(idxl, j) * kGH + c);
            a0 += (float)h[0]; a1 += (float)h[1]; a2 += (float)h[2]; a3 += (float)h[3];
        }
    }
    half4v o;
    o[0] = (_Float16)fmaxf(dv * a0 + bia.x, 0.f);
    o[1] = (_Float16)fmaxf(dv * a1 + bia.y, 0.f);
    o[2] = (_Float16)fmaxf(dv * a2 + bia.z, 0.f);
    o[3] = (_Float16)fmaxf(dv * a3 + bia.w, 0.f);
    *(half4v*)(ob + (size_t)v * kGH + c) = o;
}

// ---------------------------------------------------------------------------
// Fused mean-pool + fc:  gfc[g] = mean_{v in g}(h4[v]) @ fcW + fcb
// ---------------------------------------------------------------------------
__global__ void poolfc_kernel(const _Float16* __restrict__ h,
                              const int* __restrict__ batch1, const int* __restrict__ batch2,
                              const float* __restrict__ fcW, const float* __restrict__ fcb,
                              float* __restrict__ gfc) {
    int side = blockIdx.y;
    const _Float16* hb = h + (size_t)side * kN * kGH;
    const int* batch = side ? batch2 : batch1;
    int g = blockIdx.x;
    int lo = 0, hi = kN;
    while (lo < hi) { int mid = (lo + hi) >> 1; if (batch[mid] < g) lo = mid + 1; else hi = mid; }
    int start = lo;
    lo = start; hi = kN;
    while (lo < hi) { int mid = (lo + hi) >> 1; if (batch[mid] < g + 1) lo = mid + 1; else hi = mid; }
    int end = lo;
    int c = threadIdx.x;  // 256
    float s = 0.f;
    for (int v = start; v < end; v++) s += (float)hb[(size_t)v * kGH + c];
    __shared__ float ps[256];
    ps[c] = s / fmaxf((float)(end - start), 1.0f);
    __syncthreads();
    float acc = fcb[c];
    #pragma unroll 4
    for (int k = 0; k < kGH; k++) acc += ps[k] * fcW[(size_t)k * kGH + c];
    gfc[(size_t)(side * kG + g) * kGH + c] = acc;
}

// ---------------------------------------------------------------------------
// Generic tiled fp32 GEMM, BM=32 BN=64 (tail layers; 2x block count vs 64x64
// -> full CU coverage at M=1024/2048). K-order identical to 64-tile version.
// ---------------------------------------------------------------------------
__launch_bounds__(256)
__global__ void gemm32_kernel(const float* __restrict__ A, const float* __restrict__ B,
                              float* __restrict__ C, int M, int N, int K,
                              const float* __restrict__ bias, int relu) {
    __shared__ float As[16][32];
    __shared__ float Bs[16][64];
    int tid = threadIdx.x;
    int tx = tid & 15, ty = tid >> 4;
    int row0 = blockIdx.y * 32, col0 = blockIdx.x * 64;
    float acc[2][4] = {};
    for (int k0 = 0; k0 < K; k0 += 16) {
        {   // A tile 32x16, transposed into LDS (float2 per thread)
            int r = tid >> 3, seg = (tid & 7) * 2;
            int gr = row0 + r;
            float2 v = make_float2(0.f, 0.f);
            if (gr < M) v = *(const float2*)(A + (size_t)gr * K + k0 + seg);
            As[seg + 0][r] = v.x; As[seg + 1][r] = v.y;
        }
        {   // B tile 16x64
            int kr = tid >> 4, c4 = (tid & 15) * 4;
            float4 v = *(const float4*)(B + (size_t)(k0 + kr) * N + col0 + c4);
            *(float4*)&Bs[kr][c4] = v;
        }
        __syncthreads();
        #pragma unroll
        for (int k = 0; k < 16; k++) {
            float a[2], b[4];
            #pragma unroll
            for (int i = 0; i < 2; i++) a[i] = As[k][ty * 2 + i];
            #pragma unroll
            for (int j = 0; j < 4; j++) b[j] = Bs[k][tx * 4 + j];
            #pragma unroll
            for (int i = 0; i < 2; i++)
                #pragma unroll
                for (int j = 0; j < 4; j++)
                    acc[i][j] += a[i] * b[j];
        }
        __syncthreads();
    }
    #pragma unroll
    for (int i = 0; i < 2; i++) {
        int gr = row0 + ty * 2 + i;
        if (gr >= M) continue;
        #pragma unroll
        for (int j = 0; j < 4; j++) {
            int gc = col0 + tx * 4 + j;
            float v = acc[i][j];
            if (bias) v += bias[gc];
            if (relu) v = fmaxf(v, 0.f);
            C[(size_t)gr * N + gc] = v;
        }
    }
}

// ---------------------------------------------------------------------------
// eW1 GEMM with fused entity gather+relu on the A-load.
// ---------------------------------------------------------------------------
__launch_bounds__(256)
__global__ void gemm_entgather_kernel(const float* __restrict__ emb,
                                      const int* __restrict__ ent1, const int* __restrict__ ent2,
                                      const float* __restrict__ B, float* __restrict__ C,
                                      int N, const float* __restrict__ bias) {
    __shared__ float As[16][64];
    __shared__ float Bs[16][64];
    int tid = threadIdx.x;
    int tx = tid & 15, ty = tid >> 4;
    int row0 = blockIdx.y * 64, col0 = blockIdx.x * 64;
    float acc[4][4] = {};
    for (int k0 = 0; k0 < kEMB; k0 += 16) {
        {
            int r = tid >> 2, seg = tid & 3;
            int gr = row0 + r;                 // < 2G always
            int idx = (gr < kG) ? ent1[gr] : ent2[gr - kG];
            float4 v = *(const float4*)(emb + (size_t)idx * kEMB + k0 + seg * 4);
            As[seg * 4 + 0][r] = fmaxf(v.x, 0.f); As[seg * 4 + 1][r] = fmaxf(v.y, 0.f);
            As[seg * 4 + 2][r] = fmaxf(v.z, 0.f); As[seg * 4 + 3][r] = fmaxf(v.w, 0.f);
        }
        {
            int kr = tid >> 4, c4 = (tid & 15) * 4;
            float4 v = *(const float4*)(B + (size_t)(k0 + kr) * N + col0 + c4);
            *(float4*)&Bs[kr][c4] = v;
        }
        __syncthreads();
        #pragma unroll
        for (int k = 0; k < 16; k++) {
            float a[4], b[4];
            #pragma unroll
            for (int i = 0; i < 4; i++) a[i] = As[k][ty * 4 + i];
            #pragma unroll
            for (int j = 0; j < 4; j++) b[j] = Bs[k][tx * 4 + j];
            #pragma unroll
            for (int i = 0; i < 4; i++)
                #pragma unroll
                for (int j = 0; j < 4; j++)
                    acc[i][j] += a[i] * b[j];
        }
        __syncthreads();
    }
    #pragma unroll
    for (int i = 0; i < 4; i++) {
        int gr = row0 + ty * 4 + i;
        #pragma unroll
        for (int j = 0; j < 4; j++) {
            int gc = col0 + tx * 4 + j;
            C[(size_t)gr * N + gc] = fmaxf(acc[i][j] + bias[gc], 0.f);
        }
    }
}

// ---------------------------------------------------------------------------
// dW1 GEMM with fused egs computation on the A-load.
// ---------------------------------------------------------------------------
__launch_bounds__(256)
__global__ void gemm_egs_kernel(const float* __restrict__ gfc, const float* __restrict__ ento,
                                const float* __restrict__ B, float* __restrict__ C,
                                int N, const float* __restrict__ bias) {
    __shared__ float As[16][64];
    __shared__ float Bs[16][64];
    int tid = threadIdx.x;
    int tx = tid & 15, ty = tid >> 4;
    int row0 = blockIdx.y * 64, col0 = blockIdx.x * 64;
    float acc[4][4] = {};
    for (int k0 = 0; k0 < kHID; k0 += 16) {
        {
            int r = tid >> 2, seg = tid & 3;
            int gr = row0 + r;                 // < G always
            int k = k0 + seg * 4;
            float4 va, vb;
            if (k < kGH) {
                va = *(const float4*)(gfc + (size_t)gr * kGH + k);
                vb = *(const float4*)(gfc + (size_t)(gr + kG) * kGH + k);
            } else {
                va = *(const float4*)(ento + (size_t)gr * kEH + k - kGH);
                vb = *(const float4*)(ento + (size_t)(gr + kG) * kEH + k - kGH);
            }
            As[seg * 4 + 0][r] = fmaxf(va.x + vb.x, 0.f);
            As[seg * 4 + 1][r] = fmaxf(va.y + vb.y, 0.f);
            As[seg * 4 + 2][r] = fmaxf(va.z + vb.z, 0.f);
            As[seg * 4 + 3][r] = fmaxf(va.w + vb.w, 0.f);
        }
        {
            int kr = tid >> 4, c4 = (tid & 15) * 4;
            float4 v = *(const float4*)(B + (size_t)(k0 + kr) * N + col0 + c4);
            *(float4*)&Bs[kr][c4] = v;
        }
        __syncthreads();
        #pragma unroll
        for (int k = 0; k < 16; k++) {
            float a[4], b[4];
            #pragma unroll
            for (int i = 0; i < 4; i++) a[i] = As[k][ty * 4 + i];
            #pragma unroll
            for (int j = 0; j < 4; j++) b[j] = Bs[k][tx * 4 + j];
            #pragma unroll
            for (int i = 0; i < 4; i++)
                #pragma unroll
                for (int j = 0; j < 4; j++)
                    acc[i][j] += a[i] * b[j];
        }
        __syncthreads();
    }
    #pragma unroll
    for (int i = 0; i < 4; i++) {
        int gr = row0 + ty * 4 + i;
        #pragma unroll
        for (int j = 0; j < 4; j++) {
            int gc = col0 + tx * 4 + j;
            C[(size_t)gr * N + gc] = fmaxf(acc[i][j] + bias[gc], 0.f);
        }
    }
}

// ---------------------------------------------------------------------------
// Host launch
// ---------------------------------------------------------------------------
static inline char* carve(char*& p, size_t bytes) {
    char* r = p;
    p += (bytes + 255) & ~(size_t)255;
    return r;
}

extern "C" void kernel_launch(void* const* d_in, const int* in_sizes, int n_in,
                              void* d_out, int out_size, void* d_ws, size_t ws_size,
                              hipStream_t stream) {
    const int*   x1       = (const int*)d_in[0];
    const int*   ei1      = (const int*)d_in[1];
    const int*   ent1     = (const int*)d_in[2];
    const int*   batch1   = (const int*)d_in[3];
    const int*   x2       = (const int*)d_in[4];
    const int*   ei2      = (const int*)d_in[5];
    const int*   ent2     = (const int*)d_in[6];
    const int*   batch2   = (const int*)d_in[7];
    const float* atom_emb = (const float*)d_in[8];
    const float* gW1      = (const float*)d_in[9];
    const float* gb1      = (const float*)d_in[10];
    const float* gW2      = (const float*)d_in[11];
    const float* gb2      = (const float*)d_in[12];
    const float* fcW      = (const float*)d_in[13];
    const float* fcb      = (const float*)d_in[14];
    const float* ent_emb  = (const float*)d_in[15];
    const float* eW1      = (const float*)d_in[16];
    const float* eb1      = (const float*)d_in[17];
    const float* eW2      = (const float*)d_in[18];
    const float* eb2      = (const float*)d_in[19];
    const float* dW1      = (const float*)d_in[20];
    const float* db1      = (const float*)d_in[21];
    const float* dW2      = (const float*)d_in[22];
    const float* db2      = (const float*)d_in[23];
    const float* dW3      = (const float*)d_in[24];
    const float* db3      = (const float*)d_in[25];
    float* out = (float*)d_out;

    // Workspace carve; counts is the only zeroed span.
    char* p = (char*)d_ws;
    _Float16* h2_h   = (_Float16*)carve(p, (size_t)2 * kN * kGH * 2);  // also h4
    _Float16* hs_h   = (_Float16*)carve(p, (size_t)2 * kN * kGH * 2);
    int*   col_idx = (int*)  carve(p, (size_t)2 * kE * 4);
    int*   rankb   = (int*)  carve(p, (size_t)2 * kE * 4);
    int*   row_ptr = (int*)  carve(p, (size_t)2 * (kN + 1) * 4);
    int*   counts  = (int*)  carve(p, (size_t)2 * kN * 4);
    float* dinv    = (float*)carve(p, (size_t)2 * kN * 4);
    int2*  xd      = (int2*) carve(p, (size_t)2 * kN * 8);
    int*   bsum    = (int*)  carve(p, (size_t)2 * kNB * 4);
    int*   boff    = (int*)  carve(p, (size_t)2 * kNB * 4);
    float* M11     = (float*)carve(p, 11 * kGH * 4);
    _Float16* w2t  = (_Float16*)carve(p, (size_t)kGH * kGH * 2);
    float* gfc     = (float*)carve(p, (size_t)2 * kG * kGH * 4);
    float* etmp    = (float*)carve(p, (size_t)2 * kG * kEH * 4);
    float* ento    = (float*)carve(p, (size_t)2 * kG * kEH * 4);
    float* dh1     = (float*)carve(p, (size_t)kG * kHID * 4);
    float* dh2     = (float*)carve(p, (size_t)kG * kHID * 4);

    // --- Graph structure + conv1 (kernel boundaries = safe grid barriers) ---
    hipMemsetAsync(counts, 0, (size_t)2 * kN * 4, stream);
    prep_kernel<<<267, 256, 0, stream>>>(atom_emb, gW1, gW2, M11, w2t);
    rank_kernel<<<dim3(kE / 256, 2), 256, 0, stream>>>(ei1, ei2, counts, rankb);
    bsum_kernel<<<dim3(kNB, 2), 256, 0, stream>>>(counts, bsum);
    bscan_kernel<<<2, 256, 0, stream>>>(bsum, boff);
    scanf_kernel<<<dim3(kNB, 2), 256, 0, stream>>>(counts, boff, row_ptr, dinv, xd, x1, x2);
    scatter_kernel<<<dim3(kE / 256, 2), 256, 0, stream>>>(ei1, ei2, row_ptr, rankb, col_idx);
    conv1_combine_kernel<<<dim3((kN + 3) / 4, 2), 256, 0, stream>>>(xd, row_ptr, col_idx,
                                                                    M11, gb1, h2_h);

    // --- Conv2 GEMM (MFMA f16, BN=128): hs = dinv ⊙ (h2 @ W2) ---
    gemm2_mfma_kernel<<<dim3((kN + 127) / 128, kGH / 128, 2), 256, 0, stream>>>(h2_h, w2t,
                                                                                dinv, hs_h);
    // --- Conv2 aggregate -> h4 (reuses h2 buffer) ---
    aggregate2_kernel<<<dim3((kN + 3) / 4, 2), 256, 0, stream>>>(hs_h, dinv, row_ptr, col_idx,
                                                                 gb2, h2_h);
    // --- Fused mean-pool + fc -> gfc [2G, GH] ---
    poolfc_kernel<<<dim3(kG, 2), 256, 0, stream>>>(h2_h, batch1, batch2, fcW, fcb, gfc);

    // --- Entity encoders (gather+relu fused into eW1; eW2 on 32-row tiles) ---
    gemm_entgather_kernel<<<dim3(kEH / 64, 2 * kG / 64), 256, 0, stream>>>(ent_emb, ent1, ent2,
                                                                           eW1, etmp, kEH, eb1);
    gemm32_kernel<<<dim3(kEH / 64, 2 * kG / 32), 256, 0, stream>>>(etmp, eW2, ento,
                                                                   2 * kG, kEH, kEH, eb2, 1);
    // --- Decoder (egs fused into dW1; dW2/dW3 on 32-row tiles) ---
    gemm_egs_kernel<<<dim3(kHID / 64, kG / 64), 256, 0, stream>>>(gfc, ento, dW1, dh1,
                                                                  kHID, db1);
    gemm32_kernel<<<dim3(kHID / 64, kG / 32), 256, 0, stream>>>(dh1, dW2, dh2,
                                                                kG, kHID, kHID, db2, 1);
    gemm32_kernel<<<dim3(kOUT / 64, kG / 32), 256, 0, stream>>>(dh2, dW3, out,
                                                                kG, kOUT, kHID, db3, 0);
}